// Round 4
// baseline (626.728 us; speedup 1.0000x reference)
//
#include <hip/hip_runtime.h>
#include <math.h>

#define BATCH 4
#define NQ 2048
#define NKEY 2048
#define DMODEL 512
#define NH 8
#define DHEAD 64
#define BH (BATCH * NH)
#define VROWS 80  // 64 V rows + row 64 = rcp + rows 65..79 = 0

typedef __attribute__((ext_vector_type(8))) short short8;
typedef __attribute__((ext_vector_type(4))) float f32x4;

#define MFMA16(a, b, c) __builtin_amdgcn_mfma_f32_16x16x32_bf16((a), (b), (c), 0, 0, 0)

// f32 -> bf16 bits, round-to-nearest-even
static __device__ __forceinline__ unsigned short f2b(float f) {
    union { float f; unsigned u; } v; v.f = f;
    unsigned r = (v.u + 0x7fffu + ((v.u >> 16) & 1u)) >> 16;
    return (unsigned short)r;
}

// ---------------------------------------------------------------------------
// Cast both activations f32 -> bf16 (row-major [8192,512])
// ---------------------------------------------------------------------------
__launch_bounds__(256) __global__
void cast_x(const float* __restrict__ a, const float* __restrict__ b,
            unsigned short* __restrict__ da, unsigned short* __restrict__ db) {
    const float* s = blockIdx.y ? b : a;
    unsigned short* d = blockIdx.y ? db : da;
    size_t i = ((size_t)blockIdx.x * 256 + threadIdx.x) * 4;
    float4 v = *(const float4*)(s + i);
    ushort4 o;
    o.x = f2b(v.x); o.y = f2b(v.y); o.z = f2b(v.z); o.w = f2b(v.w);
    *(ushort4*)(d + i) = o;
}

// ---------------------------------------------------------------------------
// Transpose+cast the five 512x512 weights: Wt[n][k] = bf16(W[k][n])
// ---------------------------------------------------------------------------
__launch_bounds__(256) __global__
void trans_w(const float* __restrict__ w0, const float* __restrict__ w1,
             const float* __restrict__ w2, const float* __restrict__ w3,
             const float* __restrict__ w4, unsigned short* __restrict__ dst) {
    const float* src = (blockIdx.z == 0) ? w0 : (blockIdx.z == 1) ? w1 :
                       (blockIdx.z == 2) ? w2 : (blockIdx.z == 3) ? w3 : w4;
    unsigned short* out = dst + (size_t)blockIdx.z * DMODEL * DMODEL;
    __shared__ float t[32][33];
    const int tx = threadIdx.x & 31, ty = threadIdx.x >> 5;  // 32 x 8
    const int k0 = blockIdx.x * 32, n0 = blockIdx.y * 32;
    #pragma unroll
    for (int j = 0; j < 4; ++j)
        t[ty + j * 8][tx] = src[(size_t)(k0 + ty + j * 8) * DMODEL + n0 + tx];
    __syncthreads();
    #pragma unroll
    for (int j = 0; j < 4; ++j)
        out[(size_t)(n0 + ty + j * 8) * DMODEL + k0 + tx] = f2b(t[tx][ty + j * 8]);
}

// ---------------------------------------------------------------------------
// bf16 MFMA GEMM, direct-global fragments, 32m x 32n per wave (4096 waves at
// N=512 -> 16 waves/CU, 2x round-3 TLP). Block = 4 waves stacked on m.
// Software-pipelined fragment loads. B-frags identical across waves -> L1.
// MODE 0: head-split bf16 store  C[((b*8+h)*2048+s)*64+d]
// MODE 1: V-transposed SCALED bf16 store Vx[((b*8+h)*80+d)*2048+s] = v*scale[bh][s]
// MODE 2: bf16 store  C[m*N+n] = bf16(resid - (acc + bias[n]))
// MODE 3: f32 store   C[m*N+n] = acc + bias[n]
// ---------------------------------------------------------------------------
template <int MODE>
__launch_bounds__(256) __global__
void gemm_bf16(const unsigned short* __restrict__ A,
               const unsigned short* __restrict__ Bt,
               void* __restrict__ Cout, const float* __restrict__ bias,
               const float* __restrict__ resid, const float* __restrict__ scale,
               int M, int N, int K) {
    const int tid = threadIdx.x;
    const int w = tid >> 6, lane = tid & 63;
    const int l16 = lane & 15, q4 = lane >> 4;
    const int mBase = blockIdx.x * 128 + w * 32;
    const int n0 = blockIdx.y * 32;

    const unsigned short* Ar0 = A + (size_t)(mBase + l16) * K + q4 * 8;
    const unsigned short* Ar1 = Ar0 + (size_t)16 * K;
    const unsigned short* Br0 = Bt + (size_t)(n0 + l16) * K + q4 * 8;
    const unsigned short* Br1 = Br0 + (size_t)16 * K;

    f32x4 z = {0.f, 0.f, 0.f, 0.f};
    f32x4 acc[2][2] = {{z, z}, {z, z}};
    short8 a0 = *(const short8*)Ar0, a1 = *(const short8*)Ar1;
    short8 b0 = *(const short8*)Br0, b1 = *(const short8*)Br1;
    #pragma unroll 3
    for (int k0 = 32; k0 < K; k0 += 32) {
        short8 na0 = *(const short8*)(Ar0 + k0);
        short8 na1 = *(const short8*)(Ar1 + k0);
        short8 nb0 = *(const short8*)(Br0 + k0);
        short8 nb1 = *(const short8*)(Br1 + k0);
        acc[0][0] = MFMA16(a0, b0, acc[0][0]);
        acc[0][1] = MFMA16(a0, b1, acc[0][1]);
        acc[1][0] = MFMA16(a1, b0, acc[1][0]);
        acc[1][1] = MFMA16(a1, b1, acc[1][1]);
        a0 = na0; a1 = na1; b0 = nb0; b1 = nb1;
    }
    acc[0][0] = MFMA16(a0, b0, acc[0][0]);
    acc[0][1] = MFMA16(a0, b1, acc[0][1]);
    acc[1][0] = MFMA16(a1, b0, acc[1][0]);
    acc[1][1] = MFMA16(a1, b1, acc[1][1]);

    #pragma unroll
    for (int i = 0; i < 2; ++i) {
        #pragma unroll
        for (int t = 0; t < 2; ++t) {
            #pragma unroll
            for (int r = 0; r < 4; ++r) {
                const int m = mBase + i * 16 + q4 * 4 + r;
                const int n = n0 + t * 16 + l16;
                float v = acc[i][t][r];
                if (MODE == 0) {
                    ((unsigned short*)Cout)[(((size_t)(m >> 11) * NH + (n >> 6)) * NQ + (m & 2047)) * DHEAD + (n & 63)] = f2b(v);
                } else if (MODE == 1) {
                    const int bh = (m >> 11) * NH + (n >> 6);
                    float sc = scale[(size_t)bh * NKEY + (m & 2047)];
                    ((unsigned short*)Cout)[(((size_t)bh * VROWS) + (n & 63)) * NKEY + (m & 2047)] = f2b(v * sc);
                } else if (MODE == 2) {
                    ((unsigned short*)Cout)[(size_t)m * N + n] = f2b(resid[(size_t)m * N + n] - (v + bias[n]));
                } else {
                    ((float*)Cout)[(size_t)m * N + n] = v + bias[n];
                }
            }
        }
    }
}

// ---------------------------------------------------------------------------
// Pass 1: colSrcp[bh][k] = 1 / sum_q exp(S[q,k])  (no max subtraction; |S|<~10)
// Wave = 16 k-cols (B-frag loaded ONCE); 4096 waves. Q-frag addresses are
// identical across the 4 waves of a block -> L1 dedup.
// ---------------------------------------------------------------------------
__launch_bounds__(256) __global__
void attn_pass1(const unsigned short* __restrict__ Qh,
                const unsigned short* __restrict__ Kh,
                float* __restrict__ colSrcp) {
    const int tid = threadIdx.x;
    const int w = tid >> 6, lane = tid & 63;
    const int l16 = lane & 15, q4 = lane >> 4;
    const int bh = blockIdx.y;
    const int kcol0 = blockIdx.x * 64 + w * 16;

    const unsigned short* Krow = Kh + ((size_t)bh * NKEY + kcol0 + l16) * DHEAD;
    short8 bk0 = *(const short8*)(Krow + q4 * 8);
    short8 bk1 = *(const short8*)(Krow + 32 + q4 * 8);
    const unsigned short* Qb = Qh + (size_t)bh * NQ * DHEAD;

    f32x4 z = {0.f, 0.f, 0.f, 0.f};
    float csum = 0.f;
    #pragma unroll 2
    for (int q0 = 0; q0 < NQ; q0 += 32) {
        short8 aq[2][2];
        #pragma unroll
        for (int i = 0; i < 2; ++i) {
            const unsigned short* Arow = Qb + (size_t)(q0 + i * 16 + l16) * DHEAD;
            aq[i][0] = *(const short8*)(Arow + q4 * 8);
            aq[i][1] = *(const short8*)(Arow + 32 + q4 * 8);
        }
        #pragma unroll
        for (int i = 0; i < 2; ++i) {
            f32x4 s = MFMA16(aq[i][0], bk0, z);
            s = MFMA16(aq[i][1], bk1, s);
            csum += __expf(s[0]) + __expf(s[1]) + __expf(s[2]) + __expf(s[3]);
        }
    }
    csum += __shfl_xor(csum, 16, 64);
    csum += __shfl_xor(csum, 32, 64);
    if (q4 == 0)
        colSrcp[(size_t)bh * NKEY + kcol0 + l16] = 1.0f / csum;
}

// ---------------------------------------------------------------------------
// Fill Vx row 64 with bf16(rcp), rows 65..79 with 0 (the r_q MFMA trick rows).
// ---------------------------------------------------------------------------
__launch_bounds__(256) __global__
void fill_vx(const float* __restrict__ cs, unsigned short* __restrict__ Vx) {
    int idx = blockIdx.x * 256 + threadIdx.x;  // over BH*NKEY = 65536
    int bh = idx >> 11, k = idx & 2047;
    unsigned short* base = Vx + ((size_t)bh * VROWS + 64) * NKEY + k;
    base[0] = f2b(cs[idx]);
    #pragma unroll
    for (int r = 1; r < 16; ++r) base[(size_t)r * NKEY] = 0;
}

// ---------------------------------------------------------------------------
// Pass 2: E = exp(S) (V pre-scaled by rcp); O = E @ Vx ; col 64 of the C-tile
// row block (t=4) gives r_q = sum_k E*rcp; out = O/(1e-12+r_q).
// Wave = 16 q-rows -> 4096 waves. Double-buffered wave-private E in LDS,
// hoisted K-frags, no __syncthreads, no rcp loads/mults in the loop.
// ---------------------------------------------------------------------------
__launch_bounds__(256) __global__
void attn_pass2(const unsigned short* __restrict__ Qh,
                const unsigned short* __restrict__ Kh,
                const unsigned short* __restrict__ Vx,
                unsigned short* __restrict__ attnb) {
    __shared__ unsigned short Elds[4][2][16][40];  // [wave][buf][q][k pad40] = 10 KB
    const int tid = threadIdx.x;
    const int w = tid >> 6, lane = tid & 63;
    const int l16 = lane & 15, q4 = lane >> 4;
    const int bh = blockIdx.y;
    const int b = bh >> 3, h = bh & 7;
    const int q0w = blockIdx.x * 64 + w * 16;

    const unsigned short* Qrow = Qh + ((size_t)bh * NQ + q0w + l16) * DHEAD;
    short8 aq0 = *(const short8*)(Qrow + q4 * 8);
    short8 aq1 = *(const short8*)(Qrow + 32 + q4 * 8);
    const unsigned short* Kb = Kh + (size_t)bh * NKEY * DHEAD;
    const unsigned short* Vb = Vx + (size_t)bh * VROWS * NKEY;
    unsigned short* Ew = &Elds[w][0][0][0];

    f32x4 z = {0.f, 0.f, 0.f, 0.f};
    f32x4 o[5];
    #pragma unroll
    for (int t = 0; t < 5; ++t) o[t] = z;

    for (int k0 = 0; k0 < NKEY; k0 += 64) {
        // hoisted K-fragments for BOTH 32-k sub-tiles
        short8 bk[2][2][2];
        #pragma unroll
        for (int sub = 0; sub < 2; ++sub)
            #pragma unroll
            for (int j = 0; j < 2; ++j) {
                const unsigned short* Krow = Kb + (size_t)(k0 + sub * 32 + j * 16 + l16) * DHEAD;
                bk[sub][j][0] = *(const short8*)(Krow + q4 * 8);
                bk[sub][j][1] = *(const short8*)(Krow + 32 + q4 * 8);
            }
        #pragma unroll
        for (int sub = 0; sub < 2; ++sub) {
            const int kb = k0 + sub * 32;
            short8 bv[5];
            #pragma unroll
            for (int t = 0; t < 5; ++t)
                bv[t] = *(const short8*)(Vb + (size_t)(t * 16 + l16) * NKEY + kb + q4 * 8);
            unsigned short* Eb = Ew + sub * (16 * 40);
            #pragma unroll
            for (int j = 0; j < 2; ++j) {
                f32x4 s = MFMA16(aq0, bk[sub][j][0], z);
                s = MFMA16(aq1, bk[sub][j][1], s);
                #pragma unroll
                for (int r = 0; r < 4; ++r)
                    Eb[(q4 * 4 + r) * 40 + j * 16 + l16] = f2b(__expf(s[r]));
            }
            short8 ea = *(const short8*)(Eb + l16 * 40 + q4 * 8);
            #pragma unroll
            for (int t = 0; t < 5; ++t)
                o[t] = MFMA16(ea, bv[t], o[t]);
        }
    }

    // r_q lives in o[4] column 0 (lanes with l16==0); broadcast within quad group
    float rs[4];
    #pragma unroll
    for (int r = 0; r < 4; ++r) {
        float v = __shfl(o[4][r], q4 * 16, 64);
        rs[r] = 1.0f / (1e-12f + v);
    }
    #pragma unroll
    for (int t = 0; t < 4; ++t)
        #pragma unroll
        for (int r = 0; r < 4; ++r) {
            const int q = q0w + q4 * 4 + r;
            attnb[((size_t)b * NQ + q) * DMODEL + h * DHEAD + t * 16 + l16] =
                f2b(o[t][r] * rs[r]);
        }
}

// ---------------------------------------------------------------------------
extern "C" void kernel_launch(void* const* d_in, const int* in_sizes, int n_in,
                              void* d_out, int out_size, void* d_ws, size_t ws_size,
                              hipStream_t stream) {
    const float* init_query = (const float*)d_in[0];
    const float* embedding  = (const float*)d_in[1];
    const float* Wq = (const float*)d_in[2];
    const float* Wk = (const float*)d_in[3];
    const float* Wv = (const float*)d_in[4];
    const float* W0 = (const float*)d_in[5];
    const float* b0 = (const float*)d_in[6];
    const float* W1 = (const float*)d_in[7];
    const float* b1 = (const float*)d_in[8];
    float* out = (float*)d_out;

    const size_t ACT = (size_t)BATCH * NQ * DMODEL;   // 4M elements
    const size_t WEL = (size_t)DMODEL * DMODEL;       // 256K elements

    unsigned short* Xq   = (unsigned short*)d_ws;          // bf16 init_query
    unsigned short* Xe   = Xq + ACT;                       // bf16 embedding
    unsigned short* Wt   = Xe + ACT;                       // 5 transposed weights
    unsigned short* Qh   = Wt + 5 * WEL;                   // [bh][q][d]
    unsigned short* Kh   = Qh + ACT;                       // [bh][k][d]
    unsigned short* Vxb  = Kh + ACT;                       // [bh][80][k] scaled V + rcp row
    float* colSrcp = (float*)(Vxb + (size_t)BH * VROWS * NKEY);  // [bh][k]
    unsigned short* attnb = Xe;  // embedding dead after V-GEMM; pass2 runs later
    unsigned short* ybuf  = Xq;  // init_query bf16 dead after Q-GEMM

    unsigned short* Wqt = Wt + 0 * WEL;
    unsigned short* Wkt = Wt + 1 * WEL;
    unsigned short* Wvt = Wt + 2 * WEL;
    unsigned short* W0t = Wt + 3 * WEL;
    unsigned short* W1t = Wt + 4 * WEL;

    const int M = BATCH * NQ;  // 8192
    dim3 blk(256);
    dim3 gGemm(M / 128, DMODEL / 32);  // 64 x 16 = 1024 blocks

    cast_x<<<dim3(ACT / 1024, 2), blk, 0, stream>>>(init_query, embedding, Xq, Xe);
    trans_w<<<dim3(16, 16, 5), blk, 0, stream>>>(Wq, Wk, Wv, W0, W1, Wt);

    gemm_bf16<0><<<gGemm, blk, 0, stream>>>(Xq, Wqt, Qh, nullptr, nullptr, nullptr, M, DMODEL, DMODEL);
    gemm_bf16<0><<<gGemm, blk, 0, stream>>>(Xe, Wkt, Kh, nullptr, nullptr, nullptr, M, DMODEL, DMODEL);

    attn_pass1<<<dim3(NKEY / 64, BH), blk, 0, stream>>>(Qh, Kh, colSrcp);

    gemm_bf16<1><<<gGemm, blk, 0, stream>>>(Xe, Wvt, Vxb, nullptr, nullptr, colSrcp, M, DMODEL, DMODEL);
    fill_vx<<<dim3(BH * NKEY / 256), blk, 0, stream>>>(colSrcp, Vxb);

    attn_pass2<<<dim3(NQ / 64, BH), blk, 0, stream>>>(Qh, Kh, Vxb, attnb);

    gemm_bf16<2><<<gGemm, blk, 0, stream>>>(attnb, W0t, ybuf, b0, init_query, nullptr, M, DMODEL, DMODEL);
    gemm_bf16<3><<<gGemm, blk, 0, stream>>>(ybuf, W1t, out, b1, nullptr, nullptr, M, DMODEL, DMODEL);
}

// Round 5
// 496.665 us; speedup vs baseline: 1.2619x; 1.2619x over previous
//
#include <hip/hip_runtime.h>
#include <math.h>

#define BATCH 4
#define NQ 2048
#define NKEY 2048
#define DMODEL 512
#define NH 8
#define DHEAD 64
#define BH (BATCH * NH)
#define VROWS 80  // 64 V rows + row 64 = rcp + rows 65..79 = 0

typedef __attribute__((ext_vector_type(8))) short short8;
typedef __attribute__((ext_vector_type(4))) short short4v;
typedef __attribute__((ext_vector_type(4))) float f32x4;

#define MFMA16(a, b, c) __builtin_amdgcn_mfma_f32_16x16x32_bf16((a), (b), (c), 0, 0, 0)

#if defined(__has_builtin)
#if __has_builtin(__builtin_amdgcn_mfma_f32_16x16x16bf16_1k)
#define HAVE_MFMA16X16 1
#define MFMAK16(a, b, c) __builtin_amdgcn_mfma_f32_16x16x16bf16_1k((a), (b), (c), 0, 0, 0)
#endif
#endif

// f32 -> bf16 bits, round-to-nearest-even
static __device__ __forceinline__ unsigned short f2b(float f) {
    union { float f; unsigned u; } v; v.f = f;
    unsigned r = (v.u + 0x7fffu + ((v.u >> 16) & 1u)) >> 16;
    return (unsigned short)r;
}
static __device__ __forceinline__ float b2f(unsigned short b) {
    union { unsigned u; float f; } v; v.u = (unsigned)b << 16;
    return v.f;
}

// ---------------------------------------------------------------------------
// Cast both activations f32 -> bf16 (row-major [8192,512])
// ---------------------------------------------------------------------------
__launch_bounds__(256) __global__
void cast_x(const float* __restrict__ a, const float* __restrict__ b,
            unsigned short* __restrict__ da, unsigned short* __restrict__ db) {
    const float* s = blockIdx.y ? b : a;
    unsigned short* d = blockIdx.y ? db : da;
    size_t i = ((size_t)blockIdx.x * 256 + threadIdx.x) * 4;
    float4 v = *(const float4*)(s + i);
    ushort4 o;
    o.x = f2b(v.x); o.y = f2b(v.y); o.z = f2b(v.z); o.w = f2b(v.w);
    *(ushort4*)(d + i) = o;
}

// ---------------------------------------------------------------------------
// z=0..3: transpose+cast {Wq,Wk,Wv,W1} -> Wt[n][k]; z=4: plain cast W0 -> W0b
// ---------------------------------------------------------------------------
__launch_bounds__(256) __global__
void trans_w(const float* __restrict__ w0, const float* __restrict__ w1,
             const float* __restrict__ w2, const float* __restrict__ w3,
             const float* __restrict__ w4, unsigned short* __restrict__ dst) {
    const float* src = (blockIdx.z == 0) ? w0 : (blockIdx.z == 1) ? w1 :
                       (blockIdx.z == 2) ? w2 : (blockIdx.z == 3) ? w3 : w4;
    unsigned short* out = dst + (size_t)blockIdx.z * DMODEL * DMODEL;
    const int tx = threadIdx.x & 31, ty = threadIdx.x >> 5;  // 32 x 8
    const int k0 = blockIdx.x * 32, n0 = blockIdx.y * 32;
    if (blockIdx.z == 4) {  // plain cast, no transpose
        #pragma unroll
        for (int j = 0; j < 4; ++j)
            out[(size_t)(k0 + ty + j * 8) * DMODEL + n0 + tx] =
                f2b(src[(size_t)(k0 + ty + j * 8) * DMODEL + n0 + tx]);
        return;
    }
    __shared__ float t[32][33];
    #pragma unroll
    for (int j = 0; j < 4; ++j)
        t[ty + j * 8][tx] = src[(size_t)(k0 + ty + j * 8) * DMODEL + n0 + tx];
    __syncthreads();
    #pragma unroll
    for (int j = 0; j < 4; ++j)
        out[(size_t)(n0 + ty + j * 8) * DMODEL + k0 + tx] = f2b(t[tx][ty + j * 8]);
}

// ---------------------------------------------------------------------------
// bvec[n] = b1[n] - sum_k b0[k] * W1[k][n]
// ---------------------------------------------------------------------------
__launch_bounds__(256) __global__
void bvec_kernel(const float* __restrict__ b0, const float* __restrict__ b1,
                 const float* __restrict__ W1, float* __restrict__ bvec) {
    __shared__ float red[4][64];
    const int t = threadIdx.x;
    const int n = blockIdx.x * 64 + (t & 63);
    const int p = t >> 6;
    float s = 0.f;
    for (int k = p * 128; k < p * 128 + 128; ++k)
        s += b0[k] * W1[(size_t)k * DMODEL + n];
    red[p][t & 63] = s;
    __syncthreads();
    if (t < 64) {
        int n2 = blockIdx.x * 64 + t;
        bvec[n2] = b1[n2] - (red[0][t] + red[1][t] + red[2][t] + red[3][t]);
    }
}

// ---------------------------------------------------------------------------
// Batched GEMM: 5 z-slices in one launch (8192+ waves -> real TLP).
// Core: wave = 32m x 64n, block 128m x 64n, BK=32 (round-3 proven shape).
//  z=0: Qh  = Xq@Wqt   head-split bf16
//  z=1: Kh  = Xe@Wkt   head-split bf16
//  z=2: Vx  = Xe@Wvt   [bh][80][kc] rows 0..63, UNSCALED bf16
//  z=3: Z   = Xq@W1t + bvec   f32 [8192][512]
//  z=4: W01t= W1t@W0b^T  bf16 [512][512]  (blocks with bx>=4 idle)
// ---------------------------------------------------------------------------
__launch_bounds__(256) __global__
void qkvz_gemm(const unsigned short* __restrict__ Xq,
               const unsigned short* __restrict__ Xe,
               const unsigned short* __restrict__ Wt,  // Wqt|Wkt|Wvt|W1t|W0b|W01t
               unsigned short* __restrict__ Qh, unsigned short* __restrict__ Kh,
               unsigned short* __restrict__ Vx, float* __restrict__ Z,
               unsigned short* __restrict__ W01t, const float* __restrict__ bvec) {
    const int z = blockIdx.z;
    if (z == 4 && blockIdx.x >= 4) return;
    const size_t WEL = (size_t)DMODEL * DMODEL;
    const unsigned short* A = (z == 1 || z == 2) ? Xe : (z == 3 || z == 0) ? Xq : (Wt + 3 * WEL);
    const unsigned short* Bt = (z == 0) ? Wt : (z == 1) ? Wt + WEL : (z == 2) ? Wt + 2 * WEL :
                               (z == 3) ? Wt + 3 * WEL : Wt + 4 * WEL;
    const int K = DMODEL;
    const int tid = threadIdx.x;
    const int w = tid >> 6, lane = tid & 63;
    const int l16 = lane & 15, q4 = lane >> 4;
    const int mBase = blockIdx.x * 128 + w * 32;
    const int n0 = blockIdx.y * 64;

    const unsigned short* Arow0 = A + (size_t)(mBase + l16) * K;
    const unsigned short* Arow1 = Arow0 + (size_t)16 * K;
    const unsigned short* Brow0 = Bt + (size_t)(n0 + l16) * K;

    f32x4 zf = {0.f, 0.f, 0.f, 0.f};
    f32x4 acc[2][4];
    #pragma unroll
    for (int i = 0; i < 2; ++i)
        #pragma unroll
        for (int t = 0; t < 4; ++t) acc[i][t] = zf;

    #pragma unroll 2
    for (int k0 = 0; k0 < K; k0 += 32) {
        const int ko = k0 + q4 * 8;
        short8 a0 = *(const short8*)(Arow0 + ko);
        short8 a1 = *(const short8*)(Arow1 + ko);
        #pragma unroll
        for (int t = 0; t < 4; ++t) {
            short8 b = *(const short8*)(Brow0 + (size_t)t * 16 * K + ko);
            acc[0][t] = MFMA16(a0, b, acc[0][t]);
            acc[1][t] = MFMA16(a1, b, acc[1][t]);
        }
    }

    #pragma unroll
    for (int i = 0; i < 2; ++i) {
        #pragma unroll
        for (int t = 0; t < 4; ++t) {
            #pragma unroll
            for (int r = 0; r < 4; ++r) {
                const int m = mBase + i * 16 + q4 * 4 + r;
                const int n = n0 + t * 16 + l16;
                float v = acc[i][t][r];
                if (z == 0) {
                    Qh[(((size_t)(m >> 11) * NH + (n >> 6)) * NQ + (m & 2047)) * DHEAD + (n & 63)] = f2b(v);
                } else if (z == 1) {
                    Kh[(((size_t)(m >> 11) * NH + (n >> 6)) * NQ + (m & 2047)) * DHEAD + (n & 63)] = f2b(v);
                } else if (z == 2) {
                    const int bh = ((m >> 11) << 3) + (n >> 6);
                    Vx[((size_t)bh * VROWS + (n & 63)) * NKEY + (m & 2047)] = f2b(v);
                } else if (z == 3) {
                    Z[(size_t)m * DMODEL + n] = v + bvec[n];
                } else {
                    W01t[(size_t)m * DMODEL + n] = f2b(v);
                }
            }
        }
    }
}

// ---------------------------------------------------------------------------
// Pass 1: colSrcp[bh][k] = 1 / sum_q exp(S[q,k])   (round-3 proven shape)
// Wave = 32 k-cols, K-frags persistent; q-loop 32/iter.
// ---------------------------------------------------------------------------
__launch_bounds__(256) __global__
void attn_pass1(const unsigned short* __restrict__ Qh,
                const unsigned short* __restrict__ Kh,
                float* __restrict__ colSrcp) {
    const int tid = threadIdx.x;
    const int w = tid >> 6, lane = tid & 63;
    const int l16 = lane & 15, q4 = lane >> 4;
    const int bh = blockIdx.y;
    const int kcol0 = blockIdx.x * 128 + w * 32;

    short8 bk[2][2];
    #pragma unroll
    for (int j = 0; j < 2; ++j) {
        const unsigned short* Krow = Kh + ((size_t)bh * NKEY + kcol0 + j * 16 + l16) * DHEAD;
        bk[j][0] = *(const short8*)(Krow + q4 * 8);
        bk[j][1] = *(const short8*)(Krow + 32 + q4 * 8);
    }
    const unsigned short* Qb = Qh + (size_t)bh * NQ * DHEAD;

    f32x4 z = {0.f, 0.f, 0.f, 0.f};
    float csum[2] = {0.f, 0.f};
    #pragma unroll 2
    for (int q0 = 0; q0 < NQ; q0 += 32) {
        short8 aq[2][2];
        #pragma unroll
        for (int i = 0; i < 2; ++i) {
            const unsigned short* Arow = Qb + (size_t)(q0 + i * 16 + l16) * DHEAD;
            aq[i][0] = *(const short8*)(Arow + q4 * 8);
            aq[i][1] = *(const short8*)(Arow + 32 + q4 * 8);
        }
        #pragma unroll
        for (int i = 0; i < 2; ++i) {
            #pragma unroll
            for (int j = 0; j < 2; ++j) {
                f32x4 s = MFMA16(aq[i][0], bk[j][0], z);
                s = MFMA16(aq[i][1], bk[j][1], s);
                csum[j] += __expf(s[0]) + __expf(s[1]) + __expf(s[2]) + __expf(s[3]);
            }
        }
    }
    #pragma unroll
    for (int j = 0; j < 2; ++j) {
        float c = csum[j];
        c += __shfl_xor(c, 16, 64);
        c += __shfl_xor(c, 32, 64);
        if (q4 == 0)
            colSrcp[(size_t)bh * NKEY + kcol0 + j * 16 + l16] = 1.0f / c;
    }
}

// ---------------------------------------------------------------------------
// Scale Vx rows 0..63 by rcp[kc]; row 64 = bf16(rcp); rows 65..79 = 0.
// ---------------------------------------------------------------------------
__launch_bounds__(256) __global__
void vscale_fill(const float* __restrict__ colSrcp, unsigned short* __restrict__ Vx) {
    const int d = blockIdx.x, bh = blockIdx.y;
    unsigned short* row = Vx + ((size_t)bh * VROWS + d) * NKEY;
    const float* cs = colSrcp + (size_t)bh * NKEY;
    const int idx = threadIdx.x * 8;
    short8 o;
    if (d < 64) {
        short8 v = *(const short8*)(row + idx);
        #pragma unroll
        for (int e = 0; e < 8; ++e)
            o[e] = (short)f2b(b2f((unsigned short)v[e]) * cs[idx + e]);
    } else if (d == 64) {
        #pragma unroll
        for (int e = 0; e < 8; ++e)
            o[e] = (short)f2b(cs[idx + e]);
    } else {
        #pragma unroll
        for (int e = 0; e < 8; ++e) o[e] = 0;
    }
    *(short8*)(row + idx) = o;
}

// ---------------------------------------------------------------------------
// Pass 2, S^T formulation. Wave = 32 q-rows (2 tiles of 16).
// S^T tile = MFMA(A=K-frag, B=Q-frag): lane holds E[q=l16][kc=q4*4+r] after exp
// == EXACTLY the A-operand of mfma 16x16x16 -> PV with ZERO data movement.
// Vx pre-scaled by rcp; tile t=4 col 0 accumulates r_q via the rcp row.
// ---------------------------------------------------------------------------
__launch_bounds__(256) __global__
void attn_pass2(const unsigned short* __restrict__ Qh,
                const unsigned short* __restrict__ Kh,
                const unsigned short* __restrict__ Vx,
                unsigned short* __restrict__ attnb) {
#ifndef HAVE_MFMA16X16
    __shared__ unsigned short Elds[4][32][40];
#endif
    const int tid = threadIdx.x;
    const int w = tid >> 6, lane = tid & 63;
    const int l16 = lane & 15, q4 = lane >> 4;
    const int bh = blockIdx.y;
    const int b = bh >> 3, h = bh & 7;
    const int q0w = blockIdx.x * 128 + w * 32;

    // persistent Q B-fragments (2 q-tiles x 2 d-halves)
    short8 bq[2][2];
    #pragma unroll
    for (int i = 0; i < 2; ++i) {
        const unsigned short* Qrow = Qh + ((size_t)bh * NQ + q0w + i * 16 + l16) * DHEAD;
        bq[i][0] = *(const short8*)(Qrow + q4 * 8);
        bq[i][1] = *(const short8*)(Qrow + 32 + q4 * 8);
    }
    const unsigned short* Kb = Kh + (size_t)bh * NKEY * DHEAD;
    const unsigned short* Vb = Vx + (size_t)bh * VROWS * NKEY;

    f32x4 z = {0.f, 0.f, 0.f, 0.f};
    f32x4 o[2][5];
    #pragma unroll
    for (int i = 0; i < 2; ++i)
        #pragma unroll
        for (int t = 0; t < 5; ++t) o[i][t] = z;

    for (int k0 = 0; k0 < NKEY; k0 += 32) {
        // K A-fragments for two 16-kc micro-steps
        short8 ak[2][2];
        #pragma unroll
        for (int sub = 0; sub < 2; ++sub) {
            const unsigned short* Krow = Kb + (size_t)(k0 + sub * 16 + l16) * DHEAD;
            ak[sub][0] = *(const short8*)(Krow + q4 * 8);
            ak[sub][1] = *(const short8*)(Krow + 32 + q4 * 8);
        }
#ifdef HAVE_MFMA16X16
        short4v bv[2][5];
        #pragma unroll
        for (int sub = 0; sub < 2; ++sub)
            #pragma unroll
            for (int t = 0; t < 5; ++t)
                bv[sub][t] = *(const short4v*)(Vb + (size_t)(t * 16 + l16) * NKEY + k0 + sub * 16 + q4 * 4);
        #pragma unroll
        for (int sub = 0; sub < 2; ++sub) {
            #pragma unroll
            for (int i = 0; i < 2; ++i) {
                f32x4 s = MFMA16(ak[sub][0], bq[i][0], z);
                s = MFMA16(ak[sub][1], bq[i][1], s);
                short4v ea;
                #pragma unroll
                for (int r = 0; r < 4; ++r) ea[r] = (short)f2b(__expf(s[r]));
                #pragma unroll
                for (int t = 0; t < 5; ++t)
                    o[i][t] = MFMAK16(ea, bv[sub][t], o[i][t]);
            }
        }
#else
        short8 bv8[5];
        #pragma unroll
        for (int t = 0; t < 5; ++t)
            bv8[t] = *(const short8*)(Vb + (size_t)(t * 16 + l16) * NKEY + k0 + q4 * 8);
        unsigned short* Ew = &Elds[w][0][0];
        #pragma unroll
        for (int sub = 0; sub < 2; ++sub) {
            #pragma unroll
            for (int i = 0; i < 2; ++i) {
                f32x4 s = MFMA16(ak[sub][0], bq[i][0], z);
                s = MFMA16(ak[sub][1], bq[i][1], s);
                short4v ev;
                #pragma unroll
                for (int r = 0; r < 4; ++r) ev[r] = (short)f2b(__expf(s[r]));
                *(short4v*)(Ew + (size_t)(i * 16 + l16) * 40 + sub * 16 + q4 * 4) = ev;
            }
        }
        #pragma unroll
        for (int i = 0; i < 2; ++i) {
            short8 ea8 = *(const short8*)(Ew + (size_t)(i * 16 + l16) * 40 + q4 * 8);
            #pragma unroll
            for (int t = 0; t < 5; ++t)
                o[i][t] = MFMA16(ea8, bv8[t], o[i][t]);
        }
#endif
    }

    #pragma unroll
    for (int i = 0; i < 2; ++i) {
        float rs[4];
        #pragma unroll
        for (int r = 0; r < 4; ++r) {
            float v = __shfl(o[i][4][r], (lane & 48), 64);  // src lane q4*16 (d_local=0)
            rs[r] = 1.0f / (1e-12f + v);
        }
        #pragma unroll
        for (int t = 0; t < 4; ++t)
            #pragma unroll
            for (int r = 0; r < 4; ++r) {
                const int q = q0w + i * 16 + q4 * 4 + r;
                attnb[((size_t)b * NQ + q) * DMODEL + h * DHEAD + t * 16 + l16] =
                    f2b(o[i][t][r] * rs[r]);
            }
    }
}

// ---------------------------------------------------------------------------
// Final: out[m][n] = Z[m][n] - sum_k attnb[m][k] * W01t[n][k]   (f32 out)
// ---------------------------------------------------------------------------
__launch_bounds__(256) __global__
void final_gemm(const unsigned short* __restrict__ A,
                const unsigned short* __restrict__ Bt,
                const float* __restrict__ Z, float* __restrict__ out) {
    const int K = DMODEL;
    const int tid = threadIdx.x;
    const int w = tid >> 6, lane = tid & 63;
    const int l16 = lane & 15, q4 = lane >> 4;
    const int mBase = blockIdx.x * 128 + w * 32;
    const int n0 = blockIdx.y * 64;

    const unsigned short* Arow0 = A + (size_t)(mBase + l16) * K;
    const unsigned short* Arow1 = Arow0 + (size_t)16 * K;
    const unsigned short* Brow0 = Bt + (size_t)(n0 + l16) * K;

    f32x4 zf = {0.f, 0.f, 0.f, 0.f};
    f32x4 acc[2][4];
    #pragma unroll
    for (int i = 0; i < 2; ++i)
        #pragma unroll
        for (int t = 0; t < 4; ++t) acc[i][t] = zf;

    #pragma unroll 2
    for (int k0 = 0; k0 < K; k0 += 32) {
        const int ko = k0 + q4 * 8;
        short8 a0 = *(const short8*)(Arow0 + ko);
        short8 a1 = *(const short8*)(Arow1 + ko);
        #pragma unroll
        for (int t = 0; t < 4; ++t) {
            short8 b = *(const short8*)(Brow0 + (size_t)t * 16 * K + ko);
            acc[0][t] = MFMA16(a0, b, acc[0][t]);
            acc[1][t] = MFMA16(a1, b, acc[1][t]);
        }
    }
    #pragma unroll
    for (int i = 0; i < 2; ++i)
        #pragma unroll
        for (int t = 0; t < 4; ++t)
            #pragma unroll
            for (int r = 0; r < 4; ++r) {
                const int m = mBase + i * 16 + q4 * 4 + r;
                const int n = n0 + t * 16 + l16;
                out[(size_t)m * DMODEL + n] = Z[(size_t)m * DMODEL + n] - acc[i][t][r];
            }
}

// ---------------------------------------------------------------------------
extern "C" void kernel_launch(void* const* d_in, const int* in_sizes, int n_in,
                              void* d_out, int out_size, void* d_ws, size_t ws_size,
                              hipStream_t stream) {
    const float* init_query = (const float*)d_in[0];
    const float* embedding  = (const float*)d_in[1];
    const float* Wq = (const float*)d_in[2];
    const float* Wk = (const float*)d_in[3];
    const float* Wv = (const float*)d_in[4];
    const float* W0 = (const float*)d_in[5];
    const float* b0 = (const float*)d_in[6];
    const float* W1 = (const float*)d_in[7];
    const float* b1 = (const float*)d_in[8];
    float* out = (float*)d_out;

    const size_t ACT = (size_t)BATCH * NQ * DMODEL;   // 4M elements
    const size_t WEL = (size_t)DMODEL * DMODEL;       // 256K elements

    unsigned short* Xq  = (unsigned short*)d_ws;           // bf16 init_query
    unsigned short* Xe  = Xq + ACT;                        // bf16 embedding
    unsigned short* Wt  = Xe + ACT;                        // Wqt|Wkt|Wvt|W1t|W0b|W01t
    unsigned short* Qh  = Wt + 6 * WEL;                    // [bh][q][d]
    unsigned short* Kh  = Qh + ACT;                        // [bh][k][d]
    unsigned short* Vx  = Kh + ACT;                        // [bh][80][kc]
    float* colSrcp = (float*)(Vx + (size_t)BH * VROWS * NKEY);  // [bh][kc]
    float* Z    = colSrcp + (size_t)BH * NKEY;             // [8192][512] f32
    float* bvec = Z + ACT;                                 // [512]
    unsigned short* W01t = Wt + 5 * WEL;
    unsigned short* attnb = Xe;  // Xe dead after qkvz_gemm; pass2 runs later

    dim3 blk(256);

    cast_x<<<dim3(ACT / 1024, 2), blk, 0, stream>>>(init_query, embedding, Xq, Xe);
    trans_w<<<dim3(16, 16, 5), blk, 0, stream>>>(Wq, Wk, Wv, W1, W0, Wt);
    bvec_kernel<<<dim3(8), blk, 0, stream>>>(b0, b1, W1, bvec);

    qkvz_gemm<<<dim3(64, 8, 5), blk, 0, stream>>>(Xq, Xe, Wt, Qh, Kh, Vx, Z, W01t, bvec);

    attn_pass1<<<dim3(16, 32), blk, 0, stream>>>(Qh, Kh, colSrcp);
    vscale_fill<<<dim3(80, 32), blk, 0, stream>>>(colSrcp, Vx);
    attn_pass2<<<dim3(16, 32), blk, 0, stream>>>(Qh, Kh, Vx, attnb);

    final_gemm<<<dim3(64, 8), blk, 0, stream>>>(attnb, W01t, Z, out);
}

// Round 6
// 485.589 us; speedup vs baseline: 1.2907x; 1.0228x over previous
//
#include <hip/hip_runtime.h>
#include <math.h>

#define BATCH 4
#define NQ 2048
#define NKEY 2048
#define DMODEL 512
#define NH 8
#define DHEAD 64
#define BH (BATCH * NH)

typedef __attribute__((ext_vector_type(8))) short short8;
typedef __attribute__((ext_vector_type(4))) short short4v;
typedef __attribute__((ext_vector_type(4))) float f32x4;

#define MFMA16(a, b, c) __builtin_amdgcn_mfma_f32_16x16x32_bf16((a), (b), (c), 0, 0, 0)

#if defined(__has_builtin)
#if __has_builtin(__builtin_amdgcn_mfma_f32_16x16x16bf16_1k)
#define HAVE_MFMA16X16 1
#define MFMAK16(a, b, c) __builtin_amdgcn_mfma_f32_16x16x16bf16_1k((a), (b), (c), 0, 0, 0)
#endif
#endif

// f32 -> bf16 bits, round-to-nearest-even
static __device__ __forceinline__ unsigned short f2b(float f) {
    union { float f; unsigned u; } v; v.f = f;
    unsigned r = (v.u + 0x7fffu + ((v.u >> 16) & 1u)) >> 16;
    return (unsigned short)r;
}

// ---------------------------------------------------------------------------
// Cast both activations f32 -> bf16 (row-major [8192,512])
// ---------------------------------------------------------------------------
__launch_bounds__(256) __global__
void cast_x(const float* __restrict__ a, const float* __restrict__ b,
            unsigned short* __restrict__ da, unsigned short* __restrict__ db) {
    const float* s = blockIdx.y ? b : a;
    unsigned short* d = blockIdx.y ? db : da;
    size_t i = ((size_t)blockIdx.x * 256 + threadIdx.x) * 4;
    float4 v = *(const float4*)(s + i);
    ushort4 o;
    o.x = f2b(v.x); o.y = f2b(v.y); o.z = f2b(v.z); o.w = f2b(v.w);
    *(ushort4*)(d + i) = o;
}

// ---------------------------------------------------------------------------
// z=0..3: transpose+cast {Wq,Wk,Wv,W1} -> Wt[n][k]; z=4: plain cast W0 -> W0b
// ---------------------------------------------------------------------------
__launch_bounds__(256) __global__
void trans_w(const float* __restrict__ w0, const float* __restrict__ w1,
             const float* __restrict__ w2, const float* __restrict__ w3,
             const float* __restrict__ w4, unsigned short* __restrict__ dst) {
    const float* src = (blockIdx.z == 0) ? w0 : (blockIdx.z == 1) ? w1 :
                       (blockIdx.z == 2) ? w2 : (blockIdx.z == 3) ? w3 : w4;
    unsigned short* out = dst + (size_t)blockIdx.z * DMODEL * DMODEL;
    const int tx = threadIdx.x & 31, ty = threadIdx.x >> 5;  // 32 x 8
    const int k0 = blockIdx.x * 32, n0 = blockIdx.y * 32;
    if (blockIdx.z == 4) {  // plain cast, no transpose
        #pragma unroll
        for (int j = 0; j < 4; ++j)
            out[(size_t)(k0 + ty + j * 8) * DMODEL + n0 + tx] =
                f2b(src[(size_t)(k0 + ty + j * 8) * DMODEL + n0 + tx]);
        return;
    }
    __shared__ float t[32][33];
    #pragma unroll
    for (int j = 0; j < 4; ++j)
        t[ty + j * 8][tx] = src[(size_t)(k0 + ty + j * 8) * DMODEL + n0 + tx];
    __syncthreads();
    #pragma unroll
    for (int j = 0; j < 4; ++j)
        out[(size_t)(n0 + ty + j * 8) * DMODEL + k0 + tx] = f2b(t[tx][ty + j * 8]);
}

// ---------------------------------------------------------------------------
// bvec[n] = b1[n] - sum_k b0[k] * W1[k][n]
// ---------------------------------------------------------------------------
__launch_bounds__(256) __global__
void bvec_kernel(const float* __restrict__ b0, const float* __restrict__ b1,
                 const float* __restrict__ W1, float* __restrict__ bvec) {
    __shared__ float red[4][64];
    const int t = threadIdx.x;
    const int n = blockIdx.x * 64 + (t & 63);
    const int p = t >> 6;
    float s = 0.f;
    for (int k = p * 128; k < p * 128 + 128; ++k)
        s += b0[k] * W1[(size_t)k * DMODEL + n];
    red[p][t & 63] = s;
    __syncthreads();
    if (t < 64) {
        int n2 = blockIdx.x * 64 + t;
        bvec[n2] = b1[n2] - (red[0][t] + red[1][t] + red[2][t] + red[3][t]);
    }
}

// ---------------------------------------------------------------------------
// Batched GEMM: 5 z-slices in one launch (10240 waves -> real TLP).
// Core: wave = 32m x 64n, block 128m x 64n, BK=32.
//  z=0: Qh  = Xq@Wqt   head-split bf16 [bh][q][d]
//  z=1: Kh  = Xe@Wkt   head-split bf16 [bh][k][d]
//  z=2: Vx  = Xe@Wvt   V-transposed bf16 [bh][64][kc]  (UNSCALED)
//  z=3: Z   = Xq@W1t + bvec   f32 [8192][512]
//  z=4: W01t= W1t@W0b^T  bf16 [512][512]  (blocks with bx>=4 idle)
// ---------------------------------------------------------------------------
__launch_bounds__(256) __global__
void qkvz_gemm(const unsigned short* __restrict__ Xq,
               const unsigned short* __restrict__ Xe,
               const unsigned short* __restrict__ Wt,  // Wqt|Wkt|Wvt|W1t|W0b|W01t
               unsigned short* __restrict__ Qh, unsigned short* __restrict__ Kh,
               unsigned short* __restrict__ Vx, float* __restrict__ Z,
               unsigned short* __restrict__ W01t, const float* __restrict__ bvec) {
    const int z = blockIdx.z;
    if (z == 4 && blockIdx.x >= 4) return;
    const size_t WEL = (size_t)DMODEL * DMODEL;
    const unsigned short* A = (z == 1 || z == 2) ? Xe : (z == 3 || z == 0) ? Xq : (Wt + 3 * WEL);
    const unsigned short* Bt = (z == 0) ? Wt : (z == 1) ? Wt + WEL : (z == 2) ? Wt + 2 * WEL :
                               (z == 3) ? Wt + 3 * WEL : Wt + 4 * WEL;
    const int K = DMODEL;
    const int tid = threadIdx.x;
    const int w = tid >> 6, lane = tid & 63;
    const int l16 = lane & 15, q4 = lane >> 4;
    const int mBase = blockIdx.x * 128 + w * 32;
    const int n0 = blockIdx.y * 64;

    const unsigned short* Arow0 = A + (size_t)(mBase + l16) * K;
    const unsigned short* Arow1 = Arow0 + (size_t)16 * K;
    const unsigned short* Brow0 = Bt + (size_t)(n0 + l16) * K;

    f32x4 zf = {0.f, 0.f, 0.f, 0.f};
    f32x4 acc[2][4];
    #pragma unroll
    for (int i = 0; i < 2; ++i)
        #pragma unroll
        for (int t = 0; t < 4; ++t) acc[i][t] = zf;

    #pragma unroll 2
    for (int k0 = 0; k0 < K; k0 += 32) {
        const int ko = k0 + q4 * 8;
        short8 a0 = *(const short8*)(Arow0 + ko);
        short8 a1 = *(const short8*)(Arow1 + ko);
        #pragma unroll
        for (int t = 0; t < 4; ++t) {
            short8 b = *(const short8*)(Brow0 + (size_t)t * 16 * K + ko);
            acc[0][t] = MFMA16(a0, b, acc[0][t]);
            acc[1][t] = MFMA16(a1, b, acc[1][t]);
        }
    }

    #pragma unroll
    for (int i = 0; i < 2; ++i) {
        #pragma unroll
        for (int t = 0; t < 4; ++t) {
            #pragma unroll
            for (int r = 0; r < 4; ++r) {
                const int m = mBase + i * 16 + q4 * 4 + r;
                const int n = n0 + t * 16 + l16;
                float v = acc[i][t][r];
                if (z == 0) {
                    Qh[(((size_t)(m >> 11) * NH + (n >> 6)) * NQ + (m & 2047)) * DHEAD + (n & 63)] = f2b(v);
                } else if (z == 1) {
                    Kh[(((size_t)(m >> 11) * NH + (n >> 6)) * NQ + (m & 2047)) * DHEAD + (n & 63)] = f2b(v);
                } else if (z == 2) {
                    const int bh = ((m >> 11) << 3) + (n >> 6);
                    Vx[((size_t)bh * DHEAD + (n & 63)) * NKEY + (m & 2047)] = f2b(v);
                } else if (z == 3) {
                    Z[(size_t)m * DMODEL + n] = v + bvec[n];
                } else {
                    W01t[(size_t)m * DMODEL + n] = f2b(v);
                }
            }
        }
    }
}

// ---------------------------------------------------------------------------
// Pass 1, q-split x2: colPart[zh][bh][k] = sum_{q in half} exp(S[q,k])
// Wave = 32 k-cols, K-frags persistent; 4096 waves.
// ---------------------------------------------------------------------------
__launch_bounds__(256) __global__
void attn_pass1(const unsigned short* __restrict__ Qh,
                const unsigned short* __restrict__ Kh,
                float* __restrict__ colPart) {
    const int tid = threadIdx.x;
    const int w = tid >> 6, lane = tid & 63;
    const int l16 = lane & 15, q4 = lane >> 4;
    const int bh = blockIdx.y;
    const int zh = blockIdx.z;
    const int kcol0 = blockIdx.x * 128 + w * 32;

    short8 bk[2][2];
    #pragma unroll
    for (int j = 0; j < 2; ++j) {
        const unsigned short* Krow = Kh + ((size_t)bh * NKEY + kcol0 + j * 16 + l16) * DHEAD;
        bk[j][0] = *(const short8*)(Krow + q4 * 8);
        bk[j][1] = *(const short8*)(Krow + 32 + q4 * 8);
    }
    const unsigned short* Qb = Qh + (size_t)bh * NQ * DHEAD;

    f32x4 z = {0.f, 0.f, 0.f, 0.f};
    float csum[2] = {0.f, 0.f};
    const int qBeg = zh * (NQ / 2), qEnd = qBeg + NQ / 2;
    #pragma unroll 2
    for (int q0 = qBeg; q0 < qEnd; q0 += 32) {
        short8 aq[2][2];
        #pragma unroll
        for (int i = 0; i < 2; ++i) {
            const unsigned short* Arow = Qb + (size_t)(q0 + i * 16 + l16) * DHEAD;
            aq[i][0] = *(const short8*)(Arow + q4 * 8);
            aq[i][1] = *(const short8*)(Arow + 32 + q4 * 8);
        }
        #pragma unroll
        for (int i = 0; i < 2; ++i) {
            #pragma unroll
            for (int j = 0; j < 2; ++j) {
                f32x4 s = MFMA16(aq[i][0], bk[j][0], z);
                s = MFMA16(aq[i][1], bk[j][1], s);
                csum[j] += __expf(s[0]) + __expf(s[1]) + __expf(s[2]) + __expf(s[3]);
            }
        }
    }
    #pragma unroll
    for (int j = 0; j < 2; ++j) {
        float c = csum[j];
        c += __shfl_xor(c, 16, 64);
        c += __shfl_xor(c, 32, 64);
        if (q4 == 0)
            colPart[((size_t)zh * BH + bh) * NKEY + kcol0 + j * 16 + l16] = c;
    }
}

// ---------------------------------------------------------------------------
// colSrcp = 1 / (colPart[0] + colPart[1])
// ---------------------------------------------------------------------------
__launch_bounds__(256) __global__
void col_merge(const float* __restrict__ colPart, float* __restrict__ colSrcp) {
    size_t i = ((size_t)blockIdx.x * 256 + threadIdx.x) * 4;
    f32x4 a = *(const f32x4*)(colPart + i);
    f32x4 b = *(const f32x4*)(colPart + (size_t)BH * NKEY + i);
    f32x4 o;
    #pragma unroll
    for (int e = 0; e < 4; ++e) o[e] = 1.0f / (a[e] + b[e]);
    *(f32x4*)(colSrcp + i) = o;
}

// ---------------------------------------------------------------------------
// Pass 2, S^T formulation, k-split x2 (zh = blockIdx.z). Wave = 32 q-rows.
// S^T tile = MFMA(A=K-frag, B=Q-frag): lane holds S[kc=q4*4+r][q=l16];
// E = exp(S)*rcp[kc] (rcp is an f32x4 load matching kc=q4*4+r exactly);
// r_q accumulates in-lane; PV = MFMAK16 with E already in A-operand layout.
// Partial O (f32) and r -> workspace; merged by attn_merge.
// ---------------------------------------------------------------------------
__launch_bounds__(256) __global__
void attn_pass2(const unsigned short* __restrict__ Qh,
                const unsigned short* __restrict__ Kh,
                const unsigned short* __restrict__ Vx,
                const float* __restrict__ colSrcp,
                float* __restrict__ Opart, float* __restrict__ Rpart) {
#ifndef HAVE_MFMA16X16
    __shared__ unsigned short Elds[4][32][40];
#endif
    const int tid = threadIdx.x;
    const int w = tid >> 6, lane = tid & 63;
    const int l16 = lane & 15, q4 = lane >> 4;
    const int bh = blockIdx.y;
    const int zh = blockIdx.z;
    const int q0w = blockIdx.x * 128 + w * 32;

    // persistent Q B-fragments (2 q-tiles x 2 d-halves)
    short8 bq[2][2];
    #pragma unroll
    for (int i = 0; i < 2; ++i) {
        const unsigned short* Qrow = Qh + ((size_t)bh * NQ + q0w + i * 16 + l16) * DHEAD;
        bq[i][0] = *(const short8*)(Qrow + q4 * 8);
        bq[i][1] = *(const short8*)(Qrow + 32 + q4 * 8);
    }
    const unsigned short* Kb = Kh + (size_t)bh * NKEY * DHEAD;
    const unsigned short* Vb = Vx + (size_t)bh * DHEAD * NKEY;
    const float* cs = colSrcp + (size_t)bh * NKEY;

    f32x4 z = {0.f, 0.f, 0.f, 0.f};
    f32x4 o[2][4];
    #pragma unroll
    for (int i = 0; i < 2; ++i)
        #pragma unroll
        for (int t = 0; t < 4; ++t) o[i][t] = z;
    float rfl[2] = {0.f, 0.f};

    const int kBeg = zh * (NKEY / 2), kEnd = kBeg + NKEY / 2;
    for (int k0 = kBeg; k0 < kEnd; k0 += 32) {
        // K A-fragments + rcp for two 16-kc micro-steps
        short8 ak[2][2];
        f32x4 rcp4[2];
        #pragma unroll
        for (int sub = 0; sub < 2; ++sub) {
            const unsigned short* Krow = Kb + (size_t)(k0 + sub * 16 + l16) * DHEAD;
            ak[sub][0] = *(const short8*)(Krow + q4 * 8);
            ak[sub][1] = *(const short8*)(Krow + 32 + q4 * 8);
            rcp4[sub] = *(const f32x4*)(cs + k0 + sub * 16 + q4 * 4);
        }
#ifdef HAVE_MFMA16X16
        short4v bv[2][4];
        #pragma unroll
        for (int sub = 0; sub < 2; ++sub)
            #pragma unroll
            for (int t = 0; t < 4; ++t)
                bv[sub][t] = *(const short4v*)(Vb + (size_t)(t * 16 + l16) * NKEY + k0 + sub * 16 + q4 * 4);
        #pragma unroll
        for (int sub = 0; sub < 2; ++sub) {
            #pragma unroll
            for (int i = 0; i < 2; ++i) {
                f32x4 s = MFMA16(ak[sub][0], bq[i][0], z);
                s = MFMA16(ak[sub][1], bq[i][1], s);
                short4v ea;
                #pragma unroll
                for (int r = 0; r < 4; ++r) {
                    float e = __expf(s[r]) * rcp4[sub][r];
                    rfl[i] += e;
                    ea[r] = (short)f2b(e);
                }
                #pragma unroll
                for (int t = 0; t < 4; ++t)
                    o[i][t] = MFMAK16(ea, bv[sub][t], o[i][t]);
            }
        }
#else
        short8 bv8[4];
        #pragma unroll
        for (int t = 0; t < 4; ++t)
            bv8[t] = *(const short8*)(Vb + (size_t)(t * 16 + l16) * NKEY + k0 + q4 * 8);
        unsigned short* Ew = &Elds[w][0][0];
        #pragma unroll
        for (int sub = 0; sub < 2; ++sub) {
            #pragma unroll
            for (int i = 0; i < 2; ++i) {
                f32x4 s = MFMA16(ak[sub][0], bq[i][0], z);
                s = MFMA16(ak[sub][1], bq[i][1], s);
                short4v ev;
                #pragma unroll
                for (int r = 0; r < 4; ++r) {
                    float e = __expf(s[r]) * rcp4[sub][r];
                    rfl[i] += e;
                    ev[r] = (short)f2b(e);
                }
                *(short4v*)(Ew + (size_t)(i * 16 + l16) * 40 + sub * 16 + q4 * 4) = ev;
            }
        }
        #pragma unroll
        for (int i = 0; i < 2; ++i) {
            short8 ea8 = *(const short8*)(Ew + (size_t)(i * 16 + l16) * 40 + q4 * 8);
            #pragma unroll
            for (int t = 0; t < 4; ++t)
                o[i][t] = MFMA16(ea8, bv8[t], o[i][t]);
        }
#endif
    }

    // partial r: full in-wave reduce over kc groups; then store per-q
    float* Ob = Opart + ((size_t)zh * BH + bh) * NQ * DHEAD;
    float* Rb = Rpart + ((size_t)zh * BH + bh) * NQ;
    #pragma unroll
    for (int i = 0; i < 2; ++i) {
        float r = rfl[i];
        r += __shfl_xor(r, 16, 64);
        r += __shfl_xor(r, 32, 64);
        if (q4 == 0) Rb[q0w + i * 16 + l16] = r;
        #pragma unroll
        for (int t = 0; t < 4; ++t)
            #pragma unroll
            for (int rr = 0; rr < 4; ++rr)
                Ob[(size_t)(q0w + i * 16 + q4 * 4 + rr) * DHEAD + t * 16 + l16] = o[i][t][rr];
    }
}

// ---------------------------------------------------------------------------
// attnb[(b*NQ+q)*512 + h*64+d] = bf16( (O0+O1) / (1e-12 + R0+R1) )
// ---------------------------------------------------------------------------
__launch_bounds__(256) __global__
void attn_merge(const float* __restrict__ Opart, const float* __restrict__ Rpart,
                unsigned short* __restrict__ attnb) {
    const size_t HALF_O = (size_t)BH * NQ * DHEAD;
    const size_t HALF_R = (size_t)BH * NQ;
    const int m = blockIdx.x * 32 + (threadIdx.x >> 3);   // [0, BH*NQ)
    const int d0 = (threadIdx.x & 7) * 8;
    const int bh = m >> 11, q = m & 2047;
    const int b = bh >> 3, h = bh & 7;
    const float* O0 = Opart + (size_t)m * DHEAD + d0;
    const float* O1 = O0 + HALF_O;
    float rs = 1.0f / (1e-12f + Rpart[m] + Rpart[HALF_R + m]);
    unsigned short* dst = attnb + ((size_t)b * NQ + q) * DMODEL + h * DHEAD + d0;
    #pragma unroll
    for (int e = 0; e < 8; ++e)
        dst[e] = f2b((O0[e] + O1[e]) * rs);
}

// ---------------------------------------------------------------------------
// Final: out[m][n] = Z[m][n] - sum_k attnb[m][k] * W01t[n][k]   (f32 out)
// ---------------------------------------------------------------------------
__launch_bounds__(256) __global__
void final_gemm(const unsigned short* __restrict__ A,
                const unsigned short* __restrict__ Bt,
                const float* __restrict__ Z, float* __restrict__ out) {
    const int K = DMODEL;
    const int tid = threadIdx.x;
    const int w = tid >> 6, lane = tid & 63;
    const int l16 = lane & 15, q4 = lane >> 4;
    const int mBase = blockIdx.x * 128 + w * 32;
    const int n0 = blockIdx.y * 64;

    const unsigned short* Arow0 = A + (size_t)(mBase + l16) * K;
    const unsigned short* Arow1 = Arow0 + (size_t)16 * K;
    const unsigned short* Brow0 = Bt + (size_t)(n0 + l16) * K;

    f32x4 zf = {0.f, 0.f, 0.f, 0.f};
    f32x4 acc[2][4];
    #pragma unroll
    for (int i = 0; i < 2; ++i)
        #pragma unroll
        for (int t = 0; t < 4; ++t) acc[i][t] = zf;

    #pragma unroll 2
    for (int k0 = 0; k0 < K; k0 += 32) {
        const int ko = k0 + q4 * 8;
        short8 a0 = *(const short8*)(Arow0 + ko);
        short8 a1 = *(const short8*)(Arow1 + ko);
        #pragma unroll
        for (int t = 0; t < 4; ++t) {
            short8 b = *(const short8*)(Brow0 + (size_t)t * 16 * K + ko);
            acc[0][t] = MFMA16(a0, b, acc[0][t]);
            acc[1][t] = MFMA16(a1, b, acc[1][t]);
        }
    }
    #pragma unroll
    for (int i = 0; i < 2; ++i)
        #pragma unroll
        for (int t = 0; t < 4; ++t)
            #pragma unroll
            for (int r = 0; r < 4; ++r) {
                const int m = mBase + i * 16 + q4 * 4 + r;
                const int n = n0 + t * 16 + l16;
                out[(size_t)m * DMODEL + n] = Z[(size_t)m * DMODEL + n] - acc[i][t][r];
            }
}

// ---------------------------------------------------------------------------
extern "C" void kernel_launch(void* const* d_in, const int* in_sizes, int n_in,
                              void* d_out, int out_size, void* d_ws, size_t ws_size,
                              hipStream_t stream) {
    const float* init_query = (const float*)d_in[0];
    const float* embedding  = (const float*)d_in[1];
    const float* Wq = (const float*)d_in[2];
    const float* Wk = (const float*)d_in[3];
    const float* Wv = (const float*)d_in[4];
    const float* W0 = (const float*)d_in[5];
    const float* b0 = (const float*)d_in[6];
    const float* W1 = (const float*)d_in[7];
    const float* b1 = (const float*)d_in[8];
    float* out = (float*)d_out;

    const size_t ACT = (size_t)BATCH * NQ * DMODEL;   // 4M elements
    const size_t WEL = (size_t)DMODEL * DMODEL;       // 256K elements

    unsigned short* Xq  = (unsigned short*)d_ws;           // bf16 init_query
    unsigned short* Xe  = Xq + ACT;                        // bf16 embedding
    unsigned short* Wt  = Xe + ACT;                        // Wqt|Wkt|Wvt|W1t|W0b|W01t
    unsigned short* Qh  = Wt + 6 * WEL;                    // [bh][q][d]
    unsigned short* Kh  = Qh + ACT;                        // [bh][k][d]
    unsigned short* Vx  = Kh + ACT;                        // [bh][64][kc]
    float* colPart = (float*)(Vx + ACT);                   // [2][bh][kc]
    float* colSrcp = colPart + 2 * (size_t)BH * NKEY;      // [bh][kc]
    float* Z    = colSrcp + (size_t)BH * NKEY;             // [8192][512] f32
    float* bvec = Z + ACT;                                 // [512]
    float* Opart = bvec + DMODEL;                          // [2][bh][q][64] f32
    float* Rpart = Opart + 2 * (size_t)BH * NQ * DHEAD;    // [2][bh][q] f32
    unsigned short* W01t = Wt + 5 * WEL;
    unsigned short* attnb = Xe;  // Xe dead after qkvz_gemm

    dim3 blk(256);

    cast_x<<<dim3(ACT / 1024, 2), blk, 0, stream>>>(init_query, embedding, Xq, Xe);
    trans_w<<<dim3(16, 16, 5), blk, 0, stream>>>(Wq, Wk, Wv, W1, W0, Wt);
    bvec_kernel<<<dim3(8), blk, 0, stream>>>(b0, b1, W1, bvec);

    qkvz_gemm<<<dim3(64, 8, 5), blk, 0, stream>>>(Xq, Xe, Wt, Qh, Kh, Vx, Z, W01t, bvec);

    attn_pass1<<<dim3(16, 32, 2), blk, 0, stream>>>(Qh, Kh, colPart);
    col_merge<<<dim3(BH * NKEY / 1024), blk, 0, stream>>>(colPart, colSrcp);
    attn_pass2<<<dim3(16, 32, 2), blk, 0, stream>>>(Qh, Kh, Vx, colSrcp, Opart, Rpart);
    attn_merge<<<dim3(BH * NQ / 32), blk, 0, stream>>>(Opart, Rpart, attnb);

    final_gemm<<<dim3(64, 8), blk, 0, stream>>>(attnb, W01t, Z, out);
}

// Round 7
// 483.421 us; speedup vs baseline: 1.2964x; 1.0045x over previous
//
#include <hip/hip_runtime.h>
#include <math.h>

#define BATCH 4
#define NQ 2048
#define NKEY 2048
#define DMODEL 512
#define NH 8
#define DHEAD 64
#define BH (BATCH * NH)
#define VROWS 80  // 64 scaled V rows + row 64 = rcp + rows 65..79 = 0

typedef __attribute__((ext_vector_type(8))) short short8;
typedef __attribute__((ext_vector_type(4))) short short4v;
typedef __attribute__((ext_vector_type(4))) float f32x4;

#define MFMA16(a, b, c) __builtin_amdgcn_mfma_f32_16x16x32_bf16((a), (b), (c), 0, 0, 0)

#if defined(__has_builtin)
#if __has_builtin(__builtin_amdgcn_mfma_f32_16x16x16bf16_1k)
#define HAVE_MFMA16X16 1
#define MFMAK16(a, b, c) __builtin_amdgcn_mfma_f32_16x16x16bf16_1k((a), (b), (c), 0, 0, 0)
#endif
#endif

// f32 -> bf16 bits, round-to-nearest-even
static __device__ __forceinline__ unsigned short f2b(float f) {
    union { float f; unsigned u; } v; v.f = f;
    unsigned r = (v.u + 0x7fffu + ((v.u >> 16) & 1u)) >> 16;
    return (unsigned short)r;
}
static __device__ __forceinline__ float b2f(unsigned short b) {
    union { unsigned u; float f; } v; v.u = (unsigned)b << 16;
    return v.f;
}
// within a 32-chunk: MFMA slot s=(q4*8+j) holds true k = perm(s)
static __device__ __forceinline__ int kperm(int s) {
    int q4 = s >> 3, j = s & 7;
    return (j < 4) ? (q4 * 4 + j) : (16 + q4 * 4 + (j - 4));
}

// ---------------------------------------------------------------------------
// Cast both activations f32 -> bf16 (row-major [8192,512])
// ---------------------------------------------------------------------------
__launch_bounds__(256) __global__
void cast_x(const float* __restrict__ a, const float* __restrict__ b,
            unsigned short* __restrict__ da, unsigned short* __restrict__ db) {
    const float* s = blockIdx.y ? b : a;
    unsigned short* d = blockIdx.y ? db : da;
    size_t i = ((size_t)blockIdx.x * 256 + threadIdx.x) * 4;
    float4 v = *(const float4*)(s + i);
    ushort4 o;
    o.x = f2b(v.x); o.y = f2b(v.y); o.z = f2b(v.z); o.w = f2b(v.w);
    *(ushort4*)(d + i) = o;
}

// ---------------------------------------------------------------------------
// z=0..3: transpose+cast {Wq,Wk,Wv,W1} -> Wt[n][k]; z=4: plain cast W0 -> W0b
// ---------------------------------------------------------------------------
__launch_bounds__(256) __global__
void trans_w(const float* __restrict__ w0, const float* __restrict__ w1,
             const float* __restrict__ w2, const float* __restrict__ w3,
             const float* __restrict__ w4, unsigned short* __restrict__ dst) {
    const float* src = (blockIdx.z == 0) ? w0 : (blockIdx.z == 1) ? w1 :
                       (blockIdx.z == 2) ? w2 : (blockIdx.z == 3) ? w3 : w4;
    unsigned short* out = dst + (size_t)blockIdx.z * DMODEL * DMODEL;
    const int tx = threadIdx.x & 31, ty = threadIdx.x >> 5;  // 32 x 8
    const int k0 = blockIdx.x * 32, n0 = blockIdx.y * 32;
    if (blockIdx.z == 4) {  // plain cast, no transpose
        #pragma unroll
        for (int j = 0; j < 4; ++j)
            out[(size_t)(k0 + ty + j * 8) * DMODEL + n0 + tx] =
                f2b(src[(size_t)(k0 + ty + j * 8) * DMODEL + n0 + tx]);
        return;
    }
    __shared__ float t[32][33];
    #pragma unroll
    for (int j = 0; j < 4; ++j)
        t[ty + j * 8][tx] = src[(size_t)(k0 + ty + j * 8) * DMODEL + n0 + tx];
    __syncthreads();
    #pragma unroll
    for (int j = 0; j < 4; ++j)
        out[(size_t)(n0 + ty + j * 8) * DMODEL + k0 + tx] = f2b(t[tx][ty + j * 8]);
}

// ---------------------------------------------------------------------------
// bvec[n] = b1[n] - sum_k b0[k] * W1[k][n]
// ---------------------------------------------------------------------------
__launch_bounds__(256) __global__
void bvec_kernel(const float* __restrict__ b0, const float* __restrict__ b1,
                 const float* __restrict__ W1, float* __restrict__ bvec) {
    __shared__ float red[4][64];
    const int t = threadIdx.x;
    const int n = blockIdx.x * 64 + (t & 63);
    const int p = t >> 6;
    float s = 0.f;
    for (int k = p * 128; k < p * 128 + 128; ++k)
        s += b0[k] * W1[(size_t)k * DMODEL + n];
    red[p][t & 63] = s;
    __syncthreads();
    if (t < 64) {
        int n2 = blockIdx.x * 64 + t;
        bvec[n2] = b1[n2] - (red[0][t] + red[1][t] + red[2][t] + red[3][t]);
    }
}

// ---------------------------------------------------------------------------
// Batched GEMM: 5 z-slices in one launch (10240 waves).
//  z=0: Qh = Xq@Wqt  head-split bf16 [bh][q][d]
//  z=1: Kh = Xe@Wkt  head-split bf16 [bh][k][d]
//  z=2: Vt = Xe@Wvt  V-transposed bf16 [bh][64][kc]  (UNSCALED)
//  z=3: Z  = Xq@W1t + bvec   f32 [8192][512]
//  z=4: W01t= W1t@W0b^T  bf16 [512][512]  (blocks with bx>=4 idle)
// ---------------------------------------------------------------------------
__launch_bounds__(256) __global__
void qkvz_gemm(const unsigned short* __restrict__ Xq,
               const unsigned short* __restrict__ Xe,
               const unsigned short* __restrict__ Wt,
               unsigned short* __restrict__ Qh, unsigned short* __restrict__ Kh,
               unsigned short* __restrict__ Vt, float* __restrict__ Z,
               unsigned short* __restrict__ W01t, const float* __restrict__ bvec) {
    const int z = blockIdx.z;
    if (z == 4 && blockIdx.x >= 4) return;
    const size_t WEL = (size_t)DMODEL * DMODEL;
    const unsigned short* A = (z == 1 || z == 2) ? Xe : (z == 3 || z == 0) ? Xq : (Wt + 3 * WEL);
    const unsigned short* Bt = (z == 0) ? Wt : (z == 1) ? Wt + WEL : (z == 2) ? Wt + 2 * WEL :
                               (z == 3) ? Wt + 3 * WEL : Wt + 4 * WEL;
    const int K = DMODEL;
    const int tid = threadIdx.x;
    const int w = tid >> 6, lane = tid & 63;
    const int l16 = lane & 15, q4 = lane >> 4;
    const int mBase = blockIdx.x * 128 + w * 32;
    const int n0 = blockIdx.y * 64;

    const unsigned short* Arow0 = A + (size_t)(mBase + l16) * K;
    const unsigned short* Arow1 = Arow0 + (size_t)16 * K;
    const unsigned short* Brow0 = Bt + (size_t)(n0 + l16) * K;

    f32x4 zf = {0.f, 0.f, 0.f, 0.f};
    f32x4 acc[2][4];
    #pragma unroll
    for (int i = 0; i < 2; ++i)
        #pragma unroll
        for (int t = 0; t < 4; ++t) acc[i][t] = zf;

    #pragma unroll 2
    for (int k0 = 0; k0 < K; k0 += 32) {
        const int ko = k0 + q4 * 8;
        short8 a0 = *(const short8*)(Arow0 + ko);
        short8 a1 = *(const short8*)(Arow1 + ko);
        #pragma unroll
        for (int t = 0; t < 4; ++t) {
            short8 b = *(const short8*)(Brow0 + (size_t)t * 16 * K + ko);
            acc[0][t] = MFMA16(a0, b, acc[0][t]);
            acc[1][t] = MFMA16(a1, b, acc[1][t]);
        }
    }

    #pragma unroll
    for (int i = 0; i < 2; ++i) {
        #pragma unroll
        for (int t = 0; t < 4; ++t) {
            #pragma unroll
            for (int r = 0; r < 4; ++r) {
                const int m = mBase + i * 16 + q4 * 4 + r;
                const int n = n0 + t * 16 + l16;
                float v = acc[i][t][r];
                if (z == 0) {
                    Qh[(((size_t)(m >> 11) * NH + (n >> 6)) * NQ + (m & 2047)) * DHEAD + (n & 63)] = f2b(v);
                } else if (z == 1) {
                    Kh[(((size_t)(m >> 11) * NH + (n >> 6)) * NQ + (m & 2047)) * DHEAD + (n & 63)] = f2b(v);
                } else if (z == 2) {
                    const int bh = ((m >> 11) << 3) + (n >> 6);
                    Vt[((size_t)bh * DHEAD + (n & 63)) * NKEY + (m & 2047)] = f2b(v);
                } else if (z == 3) {
                    Z[(size_t)m * DMODEL + n] = v + bvec[n];
                } else {
                    W01t[(size_t)m * DMODEL + n] = f2b(v);
                }
            }
        }
    }
}

// ---------------------------------------------------------------------------
// NEW pass1: S^T tiles (A=K,B=Q) -> raw E=exp(S) -> fragment-packed P write +
// partial column sums. Wave = 32 kc (one 32-chunk), q-split x2 (zh).
// P layout: [bh][chunk(64)][qtile(128)][lane(64)][8 bf16]  (coalesced 16B/lane)
// ---------------------------------------------------------------------------
__launch_bounds__(256) __global__
void attn_pass1_p(const unsigned short* __restrict__ Qh,
                  const unsigned short* __restrict__ Kh,
                  unsigned short* __restrict__ Pf,
                  float* __restrict__ colPart) {
    const int tid = threadIdx.x;
    const int w = tid >> 6, lane = tid & 63;
    const int l16 = lane & 15, q4 = lane >> 4;
    const int bh = blockIdx.y, zh = blockIdx.z;
    const int kcol0 = blockIdx.x * 128 + w * 32;
    const int chunk = kcol0 >> 5;

    short8 ak[2][2];
    #pragma unroll
    for (int j = 0; j < 2; ++j) {
        const unsigned short* Krow = Kh + ((size_t)bh * NKEY + kcol0 + j * 16 + l16) * DHEAD;
        ak[j][0] = *(const short8*)(Krow + q4 * 8);
        ak[j][1] = *(const short8*)(Krow + 32 + q4 * 8);
    }
    const unsigned short* Qb = Qh + (size_t)bh * NQ * DHEAD;
    unsigned short* Pb = Pf + (((size_t)bh * 64 + chunk) * 128) * 512 + lane * 8;

    f32x4 z = {0.f, 0.f, 0.f, 0.f};
    float cs[2][4] = {};
    const int qt0 = zh * 64;
    #pragma unroll 2
    for (int qt = qt0; qt < qt0 + 64; ++qt) {
        const unsigned short* Qrow = Qb + (size_t)(qt * 16 + l16) * DHEAD;
        short8 bq0 = *(const short8*)(Qrow + q4 * 8);
        short8 bq1 = *(const short8*)(Qrow + 32 + q4 * 8);
        short8 P8;
        #pragma unroll
        for (int j = 0; j < 2; ++j) {
            f32x4 s = MFMA16(ak[j][0], bq0, z);
            s = MFMA16(ak[j][1], bq1, s);
            #pragma unroll
            for (int r = 0; r < 4; ++r) {
                float e = __expf(s[r]);
                cs[j][r] += e;
                P8[j * 4 + r] = (short)f2b(e);
            }
        }
        *(short8*)(Pb + (size_t)qt * 512) = P8;
    }
    #pragma unroll
    for (int j = 0; j < 2; ++j)
        #pragma unroll
        for (int r = 0; r < 4; ++r) {
            float c = cs[j][r];
            c += __shfl_xor(c, 1, 64);
            c += __shfl_xor(c, 2, 64);
            c += __shfl_xor(c, 4, 64);
            c += __shfl_xor(c, 8, 64);
            if (l16 == 0)
                colPart[((size_t)zh * BH + bh) * NKEY + kcol0 + j * 16 + q4 * 4 + r] = c;
        }
}

// ---------------------------------------------------------------------------
// colSrcp = 1 / (colPart[0] + colPart[1])
// ---------------------------------------------------------------------------
__launch_bounds__(256) __global__
void col_merge(const float* __restrict__ colPart, float* __restrict__ colSrcp) {
    size_t i = ((size_t)blockIdx.x * 256 + threadIdx.x) * 4;
    f32x4 a = *(const f32x4*)(colPart + i);
    f32x4 b = *(const f32x4*)(colPart + (size_t)BH * NKEY + i);
    f32x4 o;
    #pragma unroll
    for (int e = 0; e < 4; ++e) o[e] = 1.0f / (a[e] + b[e]);
    *(f32x4*)(colSrcp + i) = o;
}

// ---------------------------------------------------------------------------
// Vp[bh][d][chunk*32+s] = Vt[bh][d][chunk*32+kperm(s)] * rcp  (d<64)
// row 64 = rcp[kperm], rows 65..79 = 0.  Slot-permuted to match P's layout.
// ---------------------------------------------------------------------------
__launch_bounds__(256) __global__
void vperm_scale(const unsigned short* __restrict__ Vt,
                 const float* __restrict__ colSrcp,
                 unsigned short* __restrict__ Vp) {
    const int d = blockIdx.x, bh = blockIdx.y;
    const int idx = threadIdx.x * 8;
    const float* cs = colSrcp + (size_t)bh * NKEY;
    short8 o;
    if (d < 64) {
        const unsigned short* vr = Vt + ((size_t)bh * DHEAD + d) * NKEY;
        #pragma unroll
        for (int e = 0; e < 8; ++e) {
            int p = idx + e;
            int kt = (p & ~31) + kperm(p & 31);
            o[e] = (short)f2b(b2f(vr[kt]) * cs[kt]);
        }
    } else if (d == 64) {
        #pragma unroll
        for (int e = 0; e < 8; ++e) {
            int p = idx + e;
            int kt = (p & ~31) + kperm(p & 31);
            o[e] = (short)f2b(cs[kt]);
        }
    } else {
        #pragma unroll
        for (int e = 0; e < 8; ++e) o[e] = 0;
    }
    *(short8*)(Vp + ((size_t)bh * VROWS + d) * NKEY + idx) = o;
}

// ---------------------------------------------------------------------------
// NEW pass2: pure GEMM  O = P @ Vp. Wave = 32q x 80n, k-split x2.
// No exp, no QK. 10 K=32 MFMA per 7x16B loads per 32-chunk.
// ---------------------------------------------------------------------------
__launch_bounds__(256) __global__
void attn_pass2_p(const unsigned short* __restrict__ Pf,
                  const unsigned short* __restrict__ Vp,
                  float* __restrict__ Opart, float* __restrict__ Rpart) {
    const int tid = threadIdx.x;
    const int w = tid >> 6, lane = tid & 63;
    const int l16 = lane & 15, q4 = lane >> 4;
    const int bh = blockIdx.y, zh = blockIdx.z;
    const int q0w = blockIdx.x * 128 + w * 32;
    const int qt = q0w >> 4;

    const unsigned short* Vb = Vp + (size_t)bh * VROWS * NKEY;
    const unsigned short* Pbase = Pf + ((size_t)bh * 64) * 128 * 512 + lane * 8;

    f32x4 z = {0.f, 0.f, 0.f, 0.f};
    f32x4 o[2][5];
    #pragma unroll
    for (int i = 0; i < 2; ++i)
        #pragma unroll
        for (int t = 0; t < 5; ++t) o[i][t] = z;

    const int cBeg = zh * 32, cEnd = cBeg + 32;
    for (int c = cBeg; c < cEnd; ++c) {
        short8 a0 = *(const short8*)(Pbase + ((size_t)c * 128 + qt) * 512);
        short8 a1 = *(const short8*)(Pbase + ((size_t)c * 128 + qt + 1) * 512);
        const int k0 = c * 32;
        #pragma unroll
        for (int t = 0; t < 5; ++t) {
            short8 bv = *(const short8*)(Vb + (size_t)(t * 16 + l16) * NKEY + k0 + q4 * 8);
            o[0][t] = MFMA16(a0, bv, o[0][t]);
            o[1][t] = MFMA16(a1, bv, o[1][t]);
        }
    }

    float* Ob = Opart + ((size_t)zh * BH + bh) * NQ * DHEAD;
    float* Rb = Rpart + ((size_t)zh * BH + bh) * NQ;
    #pragma unroll
    for (int i = 0; i < 2; ++i) {
        if (l16 == 0) {
            #pragma unroll
            for (int r = 0; r < 4; ++r)
                Rb[q0w + i * 16 + q4 * 4 + r] = o[i][4][r];
        }
        #pragma unroll
        for (int t = 0; t < 4; ++t)
            #pragma unroll
            for (int r = 0; r < 4; ++r)
                Ob[(size_t)(q0w + i * 16 + q4 * 4 + r) * DHEAD + t * 16 + l16] = o[i][t][r];
    }
}

// ---------------------------------------------------------------------------
// FALLBACK pass1 (r6): colPart only, recompute path
// ---------------------------------------------------------------------------
__launch_bounds__(256) __global__
void attn_pass1_rec(const unsigned short* __restrict__ Qh,
                    const unsigned short* __restrict__ Kh,
                    float* __restrict__ colPart) {
    const int tid = threadIdx.x;
    const int w = tid >> 6, lane = tid & 63;
    const int l16 = lane & 15, q4 = lane >> 4;
    const int bh = blockIdx.y, zh = blockIdx.z;
    const int kcol0 = blockIdx.x * 128 + w * 32;

    short8 bk[2][2];
    #pragma unroll
    for (int j = 0; j < 2; ++j) {
        const unsigned short* Krow = Kh + ((size_t)bh * NKEY + kcol0 + j * 16 + l16) * DHEAD;
        bk[j][0] = *(const short8*)(Krow + q4 * 8);
        bk[j][1] = *(const short8*)(Krow + 32 + q4 * 8);
    }
    const unsigned short* Qb = Qh + (size_t)bh * NQ * DHEAD;
    f32x4 z = {0.f, 0.f, 0.f, 0.f};
    float csum[2] = {0.f, 0.f};
    const int qBeg = zh * (NQ / 2), qEnd = qBeg + NQ / 2;
    #pragma unroll 2
    for (int q0 = 0 + qBeg; q0 < qEnd; q0 += 32) {
        short8 aq[2][2];
        #pragma unroll
        for (int i = 0; i < 2; ++i) {
            const unsigned short* Arow = Qb + (size_t)(q0 + i * 16 + l16) * DHEAD;
            aq[i][0] = *(const short8*)(Arow + q4 * 8);
            aq[i][1] = *(const short8*)(Arow + 32 + q4 * 8);
        }
        #pragma unroll
        for (int i = 0; i < 2; ++i)
            #pragma unroll
            for (int j = 0; j < 2; ++j) {
                f32x4 s = MFMA16(aq[i][0], bk[j][0], z);
                s = MFMA16(aq[i][1], bk[j][1], s);
                csum[j] += __expf(s[0]) + __expf(s[1]) + __expf(s[2]) + __expf(s[3]);
            }
    }
    #pragma unroll
    for (int j = 0; j < 2; ++j) {
        float c = csum[j];
        c += __shfl_xor(c, 16, 64);
        c += __shfl_xor(c, 32, 64);
        if (q4 == 0)
            colPart[((size_t)zh * BH + bh) * NKEY + kcol0 + j * 16 + l16] = c;
    }
}

// ---------------------------------------------------------------------------
// FALLBACK pass2 (r6): recompute S^T, E=exp*rcp, PV via MFMAK16
// ---------------------------------------------------------------------------
__launch_bounds__(256) __global__
void attn_pass2_rec(const unsigned short* __restrict__ Qh,
                    const unsigned short* __restrict__ Kh,
                    const unsigned short* __restrict__ Vt,
                    const float* __restrict__ colSrcp,
                    float* __restrict__ Opart, float* __restrict__ Rpart) {
#ifndef HAVE_MFMA16X16
    __shared__ unsigned short Elds[4][32][40];
#endif
    const int tid = threadIdx.x;
    const int w = tid >> 6, lane = tid & 63;
    const int l16 = lane & 15, q4 = lane >> 4;
    const int bh = blockIdx.y, zh = blockIdx.z;
    const int q0w = blockIdx.x * 128 + w * 32;

    short8 bq[2][2];
    #pragma unroll
    for (int i = 0; i < 2; ++i) {
        const unsigned short* Qrow = Qh + ((size_t)bh * NQ + q0w + i * 16 + l16) * DHEAD;
        bq[i][0] = *(const short8*)(Qrow + q4 * 8);
        bq[i][1] = *(const short8*)(Qrow + 32 + q4 * 8);
    }
    const unsigned short* Kb = Kh + (size_t)bh * NKEY * DHEAD;
    const unsigned short* Vb = Vt + (size_t)bh * DHEAD * NKEY;
    const float* cs = colSrcp + (size_t)bh * NKEY;

    f32x4 z = {0.f, 0.f, 0.f, 0.f};
    f32x4 o[2][4];
    #pragma unroll
    for (int i = 0; i < 2; ++i)
        #pragma unroll
        for (int t = 0; t < 4; ++t) o[i][t] = z;
    float rfl[2] = {0.f, 0.f};

    const int kBeg = zh * (NKEY / 2), kEnd = kBeg + NKEY / 2;
    for (int k0 = kBeg; k0 < kEnd; k0 += 32) {
        short8 ak[2][2];
        f32x4 rcp4[2];
        #pragma unroll
        for (int sub = 0; sub < 2; ++sub) {
            const unsigned short* Krow = Kb + (size_t)(k0 + sub * 16 + l16) * DHEAD;
            ak[sub][0] = *(const short8*)(Krow + q4 * 8);
            ak[sub][1] = *(const short8*)(Krow + 32 + q4 * 8);
            rcp4[sub] = *(const f32x4*)(cs + k0 + sub * 16 + q4 * 4);
        }
#ifdef HAVE_MFMA16X16
        short4v bv[2][4];
        #pragma unroll
        for (int sub = 0; sub < 2; ++sub)
            #pragma unroll
            for (int t = 0; t < 4; ++t)
                bv[sub][t] = *(const short4v*)(Vb + (size_t)(t * 16 + l16) * NKEY + k0 + sub * 16 + q4 * 4);
        #pragma unroll
        for (int sub = 0; sub < 2; ++sub)
            #pragma unroll
            for (int i = 0; i < 2; ++i) {
                f32x4 s = MFMA16(ak[sub][0], bq[i][0], z);
                s = MFMA16(ak[sub][1], bq[i][1], s);
                short4v ea;
                #pragma unroll
                for (int r = 0; r < 4; ++r) {
                    float e = __expf(s[r]) * rcp4[sub][r];
                    rfl[i] += e;
                    ea[r] = (short)f2b(e);
                }
                #pragma unroll
                for (int t = 0; t < 4; ++t)
                    o[i][t] = MFMAK16(ea, bv[sub][t], o[i][t]);
            }
#else
        short8 bv8[4];
        #pragma unroll
        for (int t = 0; t < 4; ++t)
            bv8[t] = *(const short8*)(Vb + (size_t)(t * 16 + l16) * NKEY + k0 + q4 * 8);
        unsigned short* Ew = &Elds[w][0][0];
        #pragma unroll
        for (int sub = 0; sub < 2; ++sub)
            #pragma unroll
            for (int i = 0; i < 2; ++i) {
                f32x4 s = MFMA16(ak[sub][0], bq[i][0], z);
                s = MFMA16(ak[sub][1], bq[i][1], s);
                short4v ev;
                #pragma unroll
                for (int r = 0; r < 4; ++r) {
                    float e = __expf(s[r]) * rcp4[sub][r];
                    rfl[i] += e;
                    ev[r] = (short)f2b(e);
                }
                *(short4v*)(Ew + (size_t)(i * 16 + l16) * 40 + sub * 16 + q4 * 4) = ev;
            }
        #pragma unroll
        for (int i = 0; i < 2; ++i) {
            short8 ea8 = *(const short8*)(Ew + (size_t)(i * 16 + l16) * 40 + q4 * 8);
            #pragma unroll
            for (int t = 0; t < 4; ++t)
                o[i][t] = MFMA16(ea8, bv8[t], o[i][t]);
        }
#endif
    }

    float* Ob = Opart + ((size_t)zh * BH + bh) * NQ * DHEAD;
    float* Rb = Rpart + ((size_t)zh * BH + bh) * NQ;
    #pragma unroll
    for (int i = 0; i < 2; ++i) {
        float r = rfl[i];
        r += __shfl_xor(r, 16, 64);
        r += __shfl_xor(r, 32, 64);
        if (q4 == 0) Rb[q0w + i * 16 + l16] = r;
        #pragma unroll
        for (int t = 0; t < 4; ++t)
            #pragma unroll
            for (int rr = 0; rr < 4; ++rr)
                Ob[(size_t)(q0w + i * 16 + q4 * 4 + rr) * DHEAD + t * 16 + l16] = o[i][t][rr];
    }
}

// ---------------------------------------------------------------------------
// attnb[(b*NQ+q)*512 + h*64+d] = bf16( (O0+O1) / (1e-12 + R0+R1) )
// ---------------------------------------------------------------------------
__launch_bounds__(256) __global__
void attn_merge(const float* __restrict__ Opart, const float* __restrict__ Rpart,
                unsigned short* __restrict__ attnb) {
    const size_t HALF_O = (size_t)BH * NQ * DHEAD;
    const size_t HALF_R = (size_t)BH * NQ;
    const int m = blockIdx.x * 32 + (threadIdx.x >> 3);
    const int d0 = (threadIdx.x & 7) * 8;
    const int bh = m >> 11, q = m & 2047;
    const int b = bh >> 3, h = bh & 7;
    const float* O0 = Opart + (size_t)m * DHEAD + d0;
    const float* O1 = O0 + HALF_O;
    float rs = 1.0f / (1e-12f + Rpart[m] + Rpart[HALF_R + m]);
    unsigned short* dst = attnb + ((size_t)b * NQ + q) * DMODEL + h * DHEAD + d0;
    #pragma unroll
    for (int e = 0; e < 8; ++e)
        dst[e] = f2b((O0[e] + O1[e]) * rs);
}

// ---------------------------------------------------------------------------
// Final: out[m][n] = Z[m][n] - sum_k attnb[m][k] * W01t[n][k]   (f32 out)
// ---------------------------------------------------------------------------
__launch_bounds__(256) __global__
void final_gemm(const unsigned short* __restrict__ A,
                const unsigned short* __restrict__ Bt,
                const float* __restrict__ Z, float* __restrict__ out) {
    const int K = DMODEL;
    const int tid = threadIdx.x;
    const int w = tid >> 6, lane = tid & 63;
    const int l16 = lane & 15, q4 = lane >> 4;
    const int mBase = blockIdx.x * 128 + w * 32;
    const int n0 = blockIdx.y * 64;

    const unsigned short* Arow0 = A + (size_t)(mBase + l16) * K;
    const unsigned short* Arow1 = Arow0 + (size_t)16 * K;
    const unsigned short* Brow0 = Bt + (size_t)(n0 + l16) * K;

    f32x4 zf = {0.f, 0.f, 0.f, 0.f};
    f32x4 acc[2][4];
    #pragma unroll
    for (int i = 0; i < 2; ++i)
        #pragma unroll
        for (int t = 0; t < 4; ++t) acc[i][t] = zf;

    #pragma unroll 2
    for (int k0 = 0; k0 < K; k0 += 32) {
        const int ko = k0 + q4 * 8;
        short8 a0 = *(const short8*)(Arow0 + ko);
        short8 a1 = *(const short8*)(Arow1 + ko);
        #pragma unroll
        for (int t = 0; t < 4; ++t) {
            short8 b = *(const short8*)(Brow0 + (size_t)t * 16 * K + ko);
            acc[0][t] = MFMA16(a0, b, acc[0][t]);
            acc[1][t] = MFMA16(a1, b, acc[1][t]);
        }
    }
    #pragma unroll
    for (int i = 0; i < 2; ++i)
        #pragma unroll
        for (int t = 0; t < 4; ++t)
            #pragma unroll
            for (int r = 0; r < 4; ++r) {
                const int m = mBase + i * 16 + q4 * 4 + r;
                const int n = n0 + t * 16 + l16;
                out[(size_t)m * DMODEL + n] = Z[(size_t)m * DMODEL + n] - acc[i][t][r];
            }
}

// ---------------------------------------------------------------------------
extern "C" void kernel_launch(void* const* d_in, const int* in_sizes, int n_in,
                              void* d_out, int out_size, void* d_ws, size_t ws_size,
                              hipStream_t stream) {
    const float* init_query = (const float*)d_in[0];
    const float* embedding  = (const float*)d_in[1];
    const float* Wq = (const float*)d_in[2];
    const float* Wk = (const float*)d_in[3];
    const float* Wv = (const float*)d_in[4];
    const float* W0 = (const float*)d_in[5];
    const float* b0 = (const float*)d_in[6];
    const float* W1 = (const float*)d_in[7];
    const float* b1 = (const float*)d_in[8];
    float* out = (float*)d_out;

    const size_t ACT = (size_t)BATCH * NQ * DMODEL;   // 4M elements
    const size_t WEL = (size_t)DMODEL * DMODEL;       // 256K elements

    unsigned short* Xq  = (unsigned short*)d_ws;           // bf16 init_query
    unsigned short* Xe  = Xq + ACT;                        // bf16 embedding (later attnb)
    unsigned short* Wt  = Xe + ACT;                        // Wqt|Wkt|Wvt|W1t|W0b|W01t
    unsigned short* Qh  = Wt + 6 * WEL;                    // [bh][q][d]
    unsigned short* Kh  = Qh + ACT;                        // [bh][k][d]
    unsigned short* Vt  = Kh + ACT;                        // [bh][64][kc] unscaled
    unsigned short* Vp  = Vt + ACT;                        // [bh][80][kc] permuted+scaled
    float* colPart = (float*)(Vp + (size_t)BH * VROWS * NKEY);  // [2][bh][kc]
    float* colSrcp = colPart + 2 * (size_t)BH * NKEY;      // [bh][kc]
    float* Z    = colSrcp + (size_t)BH * NKEY;             // [8192][512] f32
    float* bvec = Z + ACT;                                 // [512]
    float* Opart = bvec + DMODEL;                          // [2][bh][q][64] f32
    float* Rpart = Opart + 2 * ACT;                        // [2][bh][q] f32
    unsigned short* Pf = (unsigned short*)(Rpart + 2 * (size_t)BH * NQ);  // 268 MB
    unsigned short* W01t = Wt + 5 * WEL;
    unsigned short* attnb = Xe;  // Xe dead after qkvz_gemm

    const size_t NEED_P = (size_t)((char*)(Pf + (size_t)BH * NQ * NKEY) - (char*)d_ws);
    const bool useP = ws_size >= NEED_P;

    dim3 blk(256);

    cast_x<<<dim3(ACT / 1024, 2), blk, 0, stream>>>(init_query, embedding, Xq, Xe);
    trans_w<<<dim3(16, 16, 5), blk, 0, stream>>>(Wq, Wk, Wv, W1, W0, Wt);
    bvec_kernel<<<dim3(8), blk, 0, stream>>>(b0, b1, W1, bvec);

    qkvz_gemm<<<dim3(64, 8, 5), blk, 0, stream>>>(Xq, Xe, Wt, Qh, Kh, Vt, Z, W01t, bvec);

    if (useP) {
        attn_pass1_p<<<dim3(16, 32, 2), blk, 0, stream>>>(Qh, Kh, Pf, colPart);
        col_merge<<<dim3(BH * NKEY / 1024), blk, 0, stream>>>(colPart, colSrcp);
        vperm_scale<<<dim3(VROWS, 32), blk, 0, stream>>>(Vt, colSrcp, Vp);
        attn_pass2_p<<<dim3(16, 32, 2), blk, 0, stream>>>(Pf, Vp, Opart, Rpart);
    } else {
        attn_pass1_rec<<<dim3(16, 32, 2), blk, 0, stream>>>(Qh, Kh, colPart);
        col_merge<<<dim3(BH * NKEY / 1024), blk, 0, stream>>>(colPart, colSrcp);
        attn_pass2_rec<<<dim3(16, 32, 2), blk, 0, stream>>>(Qh, Kh, Vt, colSrcp, Opart, Rpart);
    }
    attn_merge<<<dim3(BH * NQ / 32), blk, 0, stream>>>(Opart, Rpart, attnb);

    final_gemm<<<dim3(64, 8), blk, 0, stream>>>(attnb, W01t, Z, out);
}

// Round 8
// 431.528 us; speedup vs baseline: 1.4523x; 1.1203x over previous
//
#include <hip/hip_runtime.h>
#include <math.h>

#define BATCH 4
#define NQ 2048
#define NKEY 2048
#define DMODEL 512
#define NH 8
#define DHEAD 64
#define BH (BATCH * NH)
#define VROWS 80  // 64 V rows + row 64 = rcp + rows 65..79 = 0

typedef __attribute__((ext_vector_type(8))) short short8;
typedef __attribute__((ext_vector_type(4))) short short4v;
typedef __attribute__((ext_vector_type(4))) float f32x4;

#define MFMA16(a, b, c) __builtin_amdgcn_mfma_f32_16x16x32_bf16((a), (b), (c), 0, 0, 0)

#if defined(__has_builtin)
#if __has_builtin(__builtin_amdgcn_mfma_f32_16x16x16bf16_1k)
#define HAVE_MFMA16X16 1
#define MFMAK16(a, b, c) __builtin_amdgcn_mfma_f32_16x16x16bf16_1k((a), (b), (c), 0, 0, 0)
#endif
#if __has_builtin(__builtin_amdgcn_exp2f)
#define EXP2F(x) __builtin_amdgcn_exp2f(x)
#endif
#endif
#ifndef EXP2F
#define EXP2F(x) exp2f(x)
#endif

#define LOG2E 1.44269504088896340736f

// f32 -> bf16 bits, round-to-nearest-even
static __device__ __forceinline__ unsigned short f2b(float f) {
    union { float f; unsigned u; } v; v.f = f;
    unsigned r = (v.u + 0x7fffu + ((v.u >> 16) & 1u)) >> 16;
    return (unsigned short)r;
}
static __device__ __forceinline__ float b2f(unsigned short b) {
    union { unsigned u; float f; } v; v.u = (unsigned)b << 16;
    return v.f;
}
// MFMA A-slot s (=q4*8+j) holds true k = kperm(s) within a 32-chunk
static __device__ __forceinline__ int kperm(int s) {
    int q4 = s >> 3, j = s & 7;
    return (j < 4) ? (q4 * 4 + j) : (16 + q4 * 4 + (j - 4));
}
// inverse: true k -> slot
static __device__ __forceinline__ int kinv(int k) {
    return (k < 16) ? ((k >> 2) * 8 + (k & 3))
                    : (((k - 16) >> 2) * 8 + 4 + ((k - 16) & 3));
}

// ---------------------------------------------------------------------------
// Cast both activations f32 -> bf16 (row-major [8192,512])
// ---------------------------------------------------------------------------
__launch_bounds__(256) __global__
void cast_x(const float* __restrict__ a, const float* __restrict__ b,
            unsigned short* __restrict__ da, unsigned short* __restrict__ db) {
    const float* s = blockIdx.y ? b : a;
    unsigned short* d = blockIdx.y ? db : da;
    size_t i = ((size_t)blockIdx.x * 256 + threadIdx.x) * 4;
    float4 v = *(const float4*)(s + i);
    ushort4 o;
    o.x = f2b(v.x); o.y = f2b(v.y); o.z = f2b(v.z); o.w = f2b(v.w);
    *(ushort4*)(d + i) = o;
}

// ---------------------------------------------------------------------------
// z=0..3: transpose+cast {Wq,Wk,Wv,W1} -> Wt[n][k]; z=4: plain cast W0.
// z==1 (Wk) is scaled by log2(e) so exp(S) becomes a raw v_exp_f32 (exp2).
// ---------------------------------------------------------------------------
__launch_bounds__(256) __global__
void trans_w(const float* __restrict__ w0, const float* __restrict__ w1,
             const float* __restrict__ w2, const float* __restrict__ w3,
             const float* __restrict__ w4, unsigned short* __restrict__ dst) {
    const float* src = (blockIdx.z == 0) ? w0 : (blockIdx.z == 1) ? w1 :
                       (blockIdx.z == 2) ? w2 : (blockIdx.z == 3) ? w3 : w4;
    unsigned short* out = dst + (size_t)blockIdx.z * DMODEL * DMODEL;
    const float sc = (blockIdx.z == 1) ? LOG2E : 1.0f;
    const int tx = threadIdx.x & 31, ty = threadIdx.x >> 5;  // 32 x 8
    const int k0 = blockIdx.x * 32, n0 = blockIdx.y * 32;
    if (blockIdx.z == 4) {  // plain cast, no transpose
        #pragma unroll
        for (int j = 0; j < 4; ++j)
            out[(size_t)(k0 + ty + j * 8) * DMODEL + n0 + tx] =
                f2b(src[(size_t)(k0 + ty + j * 8) * DMODEL + n0 + tx]);
        return;
    }
    __shared__ float t[32][33];
    #pragma unroll
    for (int j = 0; j < 4; ++j)
        t[ty + j * 8][tx] = src[(size_t)(k0 + ty + j * 8) * DMODEL + n0 + tx];
    __syncthreads();
    #pragma unroll
    for (int j = 0; j < 4; ++j)
        out[(size_t)(n0 + ty + j * 8) * DMODEL + k0 + tx] = f2b(t[tx][ty + j * 8] * sc);
}

// ---------------------------------------------------------------------------
// bvec[n] = b1[n] - sum_k b0[k] * W1[k][n]
// ---------------------------------------------------------------------------
__launch_bounds__(256) __global__
void bvec_kernel(const float* __restrict__ b0, const float* __restrict__ b1,
                 const float* __restrict__ W1, float* __restrict__ bvec) {
    __shared__ float red[4][64];
    const int t = threadIdx.x;
    const int n = blockIdx.x * 64 + (t & 63);
    const int p = t >> 6;
    float s = 0.f;
    for (int k = p * 128; k < p * 128 + 128; ++k)
        s += b0[k] * W1[(size_t)k * DMODEL + n];
    red[p][t & 63] = s;
    __syncthreads();
    if (t < 64) {
        int n2 = blockIdx.x * 64 + t;
        bvec[n2] = b1[n2] - (red[0][t] + red[1][t] + red[2][t] + red[3][t]);
    }
}

// ---------------------------------------------------------------------------
// Batched GEMM: 5 z-slices in one launch.
//  z=0: Qh = Xq@Wqt  head-split bf16 [bh][q][d]
//  z=1: Kh = Xe@Wkt  head-split bf16 [bh][k][d]  (pre-scaled by log2e via Wkt)
//  z=2: Vp = Xe@Wvt  V-transposed bf16 [bh][80][kc] rows 0..63, UNSCALED;
//       if permV: kc position slot-permuted (kinv) to match P's MFMA layout
//  z=3: Z  = Xq@W1t + bvec   f32 [8192][512]
//  z=4: W01t= W1t@W0b^T  bf16 [512][512]  (blocks with bx>=4 idle)
// ---------------------------------------------------------------------------
__launch_bounds__(256) __global__
void qkvz_gemm(const unsigned short* __restrict__ Xq,
               const unsigned short* __restrict__ Xe,
               const unsigned short* __restrict__ Wt,
               unsigned short* __restrict__ Qh, unsigned short* __restrict__ Kh,
               unsigned short* __restrict__ Vp, float* __restrict__ Z,
               unsigned short* __restrict__ W01t, const float* __restrict__ bvec,
               int permV) {
    const int z = blockIdx.z;
    if (z == 4 && blockIdx.x >= 4) return;
    const size_t WEL = (size_t)DMODEL * DMODEL;
    const unsigned short* A = (z == 1 || z == 2) ? Xe : (z == 3 || z == 0) ? Xq : (Wt + 3 * WEL);
    const unsigned short* Bt = (z == 0) ? Wt : (z == 1) ? Wt + WEL : (z == 2) ? Wt + 2 * WEL :
                               (z == 3) ? Wt + 3 * WEL : Wt + 4 * WEL;
    const int K = DMODEL;
    const int tid = threadIdx.x;
    const int w = tid >> 6, lane = tid & 63;
    const int l16 = lane & 15, q4 = lane >> 4;
    const int mBase = blockIdx.x * 128 + w * 32;
    const int n0 = blockIdx.y * 64;

    const unsigned short* Arow0 = A + (size_t)(mBase + l16) * K;
    const unsigned short* Arow1 = Arow0 + (size_t)16 * K;
    const unsigned short* Brow0 = Bt + (size_t)(n0 + l16) * K;

    f32x4 zf = {0.f, 0.f, 0.f, 0.f};
    f32x4 acc[2][4];
    #pragma unroll
    for (int i = 0; i < 2; ++i)
        #pragma unroll
        for (int t = 0; t < 4; ++t) acc[i][t] = zf;

    #pragma unroll 2
    for (int k0 = 0; k0 < K; k0 += 32) {
        const int ko = k0 + q4 * 8;
        short8 a0 = *(const short8*)(Arow0 + ko);
        short8 a1 = *(const short8*)(Arow1 + ko);
        #pragma unroll
        for (int t = 0; t < 4; ++t) {
            short8 b = *(const short8*)(Brow0 + (size_t)t * 16 * K + ko);
            acc[0][t] = MFMA16(a0, b, acc[0][t]);
            acc[1][t] = MFMA16(a1, b, acc[1][t]);
        }
    }

    #pragma unroll
    for (int i = 0; i < 2; ++i) {
        #pragma unroll
        for (int t = 0; t < 4; ++t) {
            #pragma unroll
            for (int r = 0; r < 4; ++r) {
                const int m = mBase + i * 16 + q4 * 4 + r;
                const int n = n0 + t * 16 + l16;
                float v = acc[i][t][r];
                if (z == 0) {
                    Qh[(((size_t)(m >> 11) * NH + (n >> 6)) * NQ + (m & 2047)) * DHEAD + (n & 63)] = f2b(v);
                } else if (z == 1) {
                    Kh[(((size_t)(m >> 11) * NH + (n >> 6)) * NQ + (m & 2047)) * DHEAD + (n & 63)] = f2b(v);
                } else if (z == 2) {
                    const int bh = ((m >> 11) << 3) + (n >> 6);
                    const int mk = m & 2047;
                    const int pos = permV ? ((mk & ~31) | kinv(mk & 31)) : mk;
                    Vp[((size_t)bh * VROWS + (n & 63)) * NKEY + pos] = f2b(v);
                } else if (z == 3) {
                    Z[(size_t)m * DMODEL + n] = v + bvec[n];
                } else {
                    W01t[(size_t)m * DMODEL + n] = f2b(v);
                }
            }
        }
    }
}

// ---------------------------------------------------------------------------
// P-path pass1: for kc group [c0*32, (c0+C)*32): S^T tiles (A=K,B=Q) ->
// E=exp2(S') -> fragment-packed P + partial column sums (zh = q-half).
// P layout: [bh][c_local(C)][qt(128)][lane(64)][8 bf16], 16B/lane coalesced.
// ---------------------------------------------------------------------------
__launch_bounds__(256) __global__
void attn_pass1_p(const unsigned short* __restrict__ Qh,
                  const unsigned short* __restrict__ Kh,
                  unsigned short* __restrict__ Pf,
                  float* __restrict__ colPart, int c0, int C) {
    const int tid = threadIdx.x;
    const int w = tid >> 6, lane = tid & 63;
    const int l16 = lane & 15, q4 = lane >> 4;
    const int bh = blockIdx.y, zh = blockIdx.z;
    const int chunk_local = blockIdx.x * 4 + w;           // [0, C)
    const int kcol0 = (c0 + chunk_local) * 32;            // global kc base

    short8 ak[2][2];
    #pragma unroll
    for (int j = 0; j < 2; ++j) {
        const unsigned short* Krow = Kh + ((size_t)bh * NKEY + kcol0 + j * 16 + l16) * DHEAD;
        ak[j][0] = *(const short8*)(Krow + q4 * 8);
        ak[j][1] = *(const short8*)(Krow + 32 + q4 * 8);
    }
    const unsigned short* Qb = Qh + (size_t)bh * NQ * DHEAD;
    unsigned short* Pb = Pf + (((size_t)bh * C + chunk_local) * 128) * 512 + lane * 8;

    f32x4 z = {0.f, 0.f, 0.f, 0.f};
    float cs[2][4] = {};
    const int qt0 = zh * 64;
    #pragma unroll 2
    for (int qt = qt0; qt < qt0 + 64; ++qt) {
        const unsigned short* Qrow = Qb + (size_t)(qt * 16 + l16) * DHEAD;
        short8 bq0 = *(const short8*)(Qrow + q4 * 8);
        short8 bq1 = *(const short8*)(Qrow + 32 + q4 * 8);
        short8 P8;
        #pragma unroll
        for (int j = 0; j < 2; ++j) {
            f32x4 s = MFMA16(ak[j][0], bq0, z);
            s = MFMA16(ak[j][1], bq1, s);
            #pragma unroll
            for (int r = 0; r < 4; ++r) {
                float e = EXP2F(s[r]);
                cs[j][r] += e;
                P8[j * 4 + r] = (short)f2b(e);
            }
        }
        *(short8*)(Pb + (size_t)qt * 512) = P8;
    }
    #pragma unroll
    for (int j = 0; j < 2; ++j)
        #pragma unroll
        for (int r = 0; r < 4; ++r) {
            float c = cs[j][r];
            c += __shfl_xor(c, 1, 64);
            c += __shfl_xor(c, 2, 64);
            c += __shfl_xor(c, 4, 64);
            c += __shfl_xor(c, 8, 64);
            if (l16 == 0)
                colPart[((size_t)zh * BH + bh) * NKEY + kcol0 + j * 16 + q4 * 4 + r] = c;
        }
}

// ---------------------------------------------------------------------------
// Scale Vp rows 0..63 in place by 1/colS (permuted indexing), row 64 = rcp,
// rows 65..79 = 0, for the group's kc range only.
// ---------------------------------------------------------------------------
__launch_bounds__(256) __global__
void vscale_merge(const float* __restrict__ colPart,
                  unsigned short* __restrict__ Vp, int c0, int C) {
    const int nPer = C * 4;  // 8-element segments per row in this group
    const int idx = blockIdx.x * 256 + threadIdx.x;
    const int seg = idx % nPer;
    const int rest = idx / nPer;
    const int d = rest % VROWS;
    const int bh = rest / VROWS;
    const int base_pos = c0 * 32 + seg * 8;
    const float* cp0 = colPart + (size_t)bh * NKEY;
    const float* cp1 = cp0 + (size_t)BH * NKEY;
    unsigned short* row = Vp + ((size_t)bh * VROWS + d) * NKEY;
    short8 v;
    if (d < 64) {
        v = *(const short8*)(row + base_pos);
        #pragma unroll
        for (int e = 0; e < 8; ++e) {
            int pos = base_pos + e;
            int kt = (pos & ~31) | kperm(pos & 31);
            float rcp = 1.0f / (cp0[kt] + cp1[kt]);
            v[e] = (short)f2b(b2f((unsigned short)v[e]) * rcp);
        }
    } else if (d == 64) {
        #pragma unroll
        for (int e = 0; e < 8; ++e) {
            int pos = base_pos + e;
            int kt = (pos & ~31) | kperm(pos & 31);
            v[e] = (short)f2b(1.0f / (cp0[kt] + cp1[kt]));
        }
    } else {
        #pragma unroll
        for (int e = 0; e < 8; ++e) v[e] = 0;
    }
    *(short8*)(row + base_pos) = v;
}

// ---------------------------------------------------------------------------
// P-path pass2: pure GEMM O (+)= P @ Vp over the group's kc range.
// Wave = 32q x 80n. 2 P loads + 5 V loads + 10 K=32 MFMA per 32-chunk.
// Row 64 of Vp (rcp) gives r_q in o[i][4] col 0.
// ---------------------------------------------------------------------------
__launch_bounds__(256) __global__
void attn_pass2_p(const unsigned short* __restrict__ Pf,
                  const unsigned short* __restrict__ Vp,
                  float* __restrict__ Opart, float* __restrict__ Rpart,
                  int c0, int C, int accum) {
    const int tid = threadIdx.x;
    const int w = tid >> 6, lane = tid & 63;
    const int l16 = lane & 15, q4 = lane >> 4;
    const int bh = blockIdx.y;
    const int q0w = blockIdx.x * 128 + w * 32;
    const int qt = q0w >> 4;

    const unsigned short* Vb = Vp + (size_t)bh * VROWS * NKEY;
    const unsigned short* Pbase = Pf + ((size_t)bh * C) * 128 * 512 + lane * 8;

    f32x4 z = {0.f, 0.f, 0.f, 0.f};
    f32x4 o[2][5];
    #pragma unroll
    for (int i = 0; i < 2; ++i)
        #pragma unroll
        for (int t = 0; t < 5; ++t) o[i][t] = z;

    for (int c = 0; c < C; ++c) {
        short8 a0 = *(const short8*)(Pbase + ((size_t)c * 128 + qt) * 512);
        short8 a1 = *(const short8*)(Pbase + ((size_t)c * 128 + qt + 1) * 512);
        const int k0 = (c0 + c) * 32;
        #pragma unroll
        for (int t = 0; t < 5; ++t) {
            short8 bv = *(const short8*)(Vb + (size_t)(t * 16 + l16) * NKEY + k0 + q4 * 8);
            o[0][t] = MFMA16(a0, bv, o[0][t]);
            o[1][t] = MFMA16(a1, bv, o[1][t]);
        }
    }

    float* Ob = Opart + (size_t)bh * NQ * DHEAD;
    float* Rb = Rpart + (size_t)bh * NQ;
    #pragma unroll
    for (int i = 0; i < 2; ++i) {
        if (l16 == 0) {
            #pragma unroll
            for (int r = 0; r < 4; ++r) {
                const int q = q0w + i * 16 + q4 * 4 + r;
                Rb[q] = accum ? (Rb[q] + o[i][4][r]) : o[i][4][r];
            }
        }
        #pragma unroll
        for (int t = 0; t < 4; ++t)
            #pragma unroll
            for (int r = 0; r < 4; ++r) {
                const size_t a = (size_t)(q0w + i * 16 + q4 * 4 + r) * DHEAD + t * 16 + l16;
                Ob[a] = accum ? (Ob[a] + o[i][t][r]) : o[i][t][r];
            }
    }
}

// ---------------------------------------------------------------------------
// P-path merge: attnb = bf16( O / (1e-12 + R) )  (single plane)
// ---------------------------------------------------------------------------
__launch_bounds__(256) __global__
void attn_merge_p(const float* __restrict__ Opart, const float* __restrict__ Rpart,
                  unsigned short* __restrict__ attnb) {
    const int m = blockIdx.x * 32 + (threadIdx.x >> 3);
    const int d0 = (threadIdx.x & 7) * 8;
    const int bh = m >> 11, q = m & 2047;
    const int b = bh >> 3, h = bh & 7;
    const float* O = Opart + (size_t)m * DHEAD + d0;
    float rs = 1.0f / (1e-12f + Rpart[m]);
    unsigned short* dst = attnb + ((size_t)b * NQ + q) * DMODEL + h * DHEAD + d0;
    #pragma unroll
    for (int e = 0; e < 8; ++e)
        dst[e] = f2b(O[e] * rs);
}

// ---------------------------------------------------------------------------
// FALLBACK pass1 (rec): colPart only
// ---------------------------------------------------------------------------
__launch_bounds__(256) __global__
void attn_pass1_rec(const unsigned short* __restrict__ Qh,
                    const unsigned short* __restrict__ Kh,
                    float* __restrict__ colPart) {
    const int tid = threadIdx.x;
    const int w = tid >> 6, lane = tid & 63;
    const int l16 = lane & 15, q4 = lane >> 4;
    const int bh = blockIdx.y, zh = blockIdx.z;
    const int kcol0 = blockIdx.x * 128 + w * 32;

    short8 bk[2][2];
    #pragma unroll
    for (int j = 0; j < 2; ++j) {
        const unsigned short* Krow = Kh + ((size_t)bh * NKEY + kcol0 + j * 16 + l16) * DHEAD;
        bk[j][0] = *(const short8*)(Krow + q4 * 8);
        bk[j][1] = *(const short8*)(Krow + 32 + q4 * 8);
    }
    const unsigned short* Qb = Qh + (size_t)bh * NQ * DHEAD;
    f32x4 z = {0.f, 0.f, 0.f, 0.f};
    float csum[2] = {0.f, 0.f};
    const int qBeg = zh * (NQ / 2), qEnd = qBeg + NQ / 2;
    #pragma unroll 2
    for (int q0 = qBeg; q0 < qEnd; q0 += 32) {
        short8 aq[2][2];
        #pragma unroll
        for (int i = 0; i < 2; ++i) {
            const unsigned short* Arow = Qb + (size_t)(q0 + i * 16 + l16) * DHEAD;
            aq[i][0] = *(const short8*)(Arow + q4 * 8);
            aq[i][1] = *(const short8*)(Arow + 32 + q4 * 8);
        }
        #pragma unroll
        for (int i = 0; i < 2; ++i)
            #pragma unroll
            for (int j = 0; j < 2; ++j) {
                f32x4 s = MFMA16(aq[i][0], bk[j][0], z);
                s = MFMA16(aq[i][1], bk[j][1], s);
                csum[j] += EXP2F(s[0]) + EXP2F(s[1]) + EXP2F(s[2]) + EXP2F(s[3]);
            }
    }
    #pragma unroll
    for (int j = 0; j < 2; ++j) {
        float c = csum[j];
        c += __shfl_xor(c, 16, 64);
        c += __shfl_xor(c, 32, 64);
        if (q4 == 0)
            colPart[((size_t)zh * BH + bh) * NKEY + kcol0 + j * 16 + l16] = c;
    }
}

// ---------------------------------------------------------------------------
// colSrcp = 1 / (colPart[0] + colPart[1])   (rec path only)
// ---------------------------------------------------------------------------
__launch_bounds__(256) __global__
void col_merge(const float* __restrict__ colPart, float* __restrict__ colSrcp) {
    size_t i = ((size_t)blockIdx.x * 256 + threadIdx.x) * 4;
    f32x4 a = *(const f32x4*)(colPart + i);
    f32x4 b = *(const f32x4*)(colPart + (size_t)BH * NKEY + i);
    f32x4 o;
    #pragma unroll
    for (int e = 0; e < 4; ++e) o[e] = 1.0f / (a[e] + b[e]);
    *(f32x4*)(colSrcp + i) = o;
}

// ---------------------------------------------------------------------------
// FALLBACK pass2 (rec): recompute S^T, E=exp2*rcp, PV via MFMAK16.
// Vp unpermuted rows 0..63 (VROWS stride).
// ---------------------------------------------------------------------------
__launch_bounds__(256) __global__
void attn_pass2_rec(const unsigned short* __restrict__ Qh,
                    const unsigned short* __restrict__ Kh,
                    const unsigned short* __restrict__ Vp,
                    const float* __restrict__ colSrcp,
                    float* __restrict__ Opart, float* __restrict__ Rpart) {
#ifndef HAVE_MFMA16X16
    __shared__ unsigned short Elds[4][32][40];
#endif
    const int tid = threadIdx.x;
    const int w = tid >> 6, lane = tid & 63;
    const int l16 = lane & 15, q4 = lane >> 4;
    const int bh = blockIdx.y, zh = blockIdx.z;
    const int q0w = blockIdx.x * 128 + w * 32;

    short8 bq[2][2];
    #pragma unroll
    for (int i = 0; i < 2; ++i) {
        const unsigned short* Qrow = Qh + ((size_t)bh * NQ + q0w + i * 16 + l16) * DHEAD;
        bq[i][0] = *(const short8*)(Qrow + q4 * 8);
        bq[i][1] = *(const short8*)(Qrow + 32 + q4 * 8);
    }
    const unsigned short* Kb = Kh + (size_t)bh * NKEY * DHEAD;
    const unsigned short* Vb = Vp + (size_t)bh * VROWS * NKEY;
    const float* cs = colSrcp + (size_t)bh * NKEY;

    f32x4 z = {0.f, 0.f, 0.f, 0.f};
    f32x4 o[2][4];
    #pragma unroll
    for (int i = 0; i < 2; ++i)
        #pragma unroll
        for (int t = 0; t < 4; ++t) o[i][t] = z;
    float rfl[2] = {0.f, 0.f};

    const int kBeg = zh * (NKEY / 2), kEnd = kBeg + NKEY / 2;
    for (int k0 = kBeg; k0 < kEnd; k0 += 32) {
        short8 ak[2][2];
        f32x4 rcp4[2];
        #pragma unroll
        for (int sub = 0; sub < 2; ++sub) {
            const unsigned short* Krow = Kb + (size_t)(k0 + sub * 16 + l16) * DHEAD;
            ak[sub][0] = *(const short8*)(Krow + q4 * 8);
            ak[sub][1] = *(const short8*)(Krow + 32 + q4 * 8);
            rcp4[sub] = *(const f32x4*)(cs + k0 + sub * 16 + q4 * 4);
        }
#ifdef HAVE_MFMA16X16
        short4v bv[2][4];
        #pragma unroll
        for (int sub = 0; sub < 2; ++sub)
            #pragma unroll
            for (int t = 0; t < 4; ++t)
                bv[sub][t] = *(const short4v*)(Vb + (size_t)(t * 16 + l16) * NKEY + k0 + sub * 16 + q4 * 4);
        #pragma unroll
        for (int sub = 0; sub < 2; ++sub)
            #pragma unroll
            for (int i = 0; i < 2; ++i) {
                f32x4 s = MFMA16(ak[sub][0], bq[i][0], z);
                s = MFMA16(ak[sub][1], bq[i][1], s);
                short4v ea;
                #pragma unroll
                for (int r = 0; r < 4; ++r) {
                    float e = EXP2F(s[r]) * rcp4[sub][r];
                    rfl[i] += e;
                    ea[r] = (short)f2b(e);
                }
                #pragma unroll
                for (int t = 0; t < 4; ++t)
                    o[i][t] = MFMAK16(ea, bv[sub][t], o[i][t]);
            }
#else
        short8 bv8[4];
        #pragma unroll
        for (int t = 0; t < 4; ++t)
            bv8[t] = *(const short8*)(Vb + (size_t)(t * 16 + l16) * NKEY + k0 + q4 * 8);
        unsigned short* Ew = &Elds[w][0][0];
        #pragma unroll
        for (int sub = 0; sub < 2; ++sub)
            #pragma unroll
            for (int i = 0; i < 2; ++i) {
                f32x4 s = MFMA16(ak[sub][0], bq[i][0], z);
                s = MFMA16(ak[sub][1], bq[i][1], s);
                short4v ev;
                #pragma unroll
                for (int r = 0; r < 4; ++r) {
                    float e = EXP2F(s[r]) * rcp4[sub][r];
                    rfl[i] += e;
                    ev[r] = (short)f2b(e);
                }
                *(short4v*)(Ew + (size_t)(i * 16 + l16) * 40 + sub * 16 + q4 * 4) = ev;
            }
        #pragma unroll
        for (int i = 0; i < 2; ++i) {
            short8 ea8 = *(const short8*)(Ew + (size_t)(i * 16 + l16) * 40 + q4 * 8);
            #pragma unroll
            for (int t = 0; t < 4; ++t)
                o[i][t] = MFMA16(ea8, bv8[t], o[i][t]);
        }
#endif
    }

    float* Ob = Opart + ((size_t)zh * BH + bh) * NQ * DHEAD;
    float* Rb = Rpart + ((size_t)zh * BH + bh) * NQ;
    #pragma unroll
    for (int i = 0; i < 2; ++i) {
        float r = rfl[i];
        r += __shfl_xor(r, 16, 64);
        r += __shfl_xor(r, 32, 64);
        if (q4 == 0) Rb[q0w + i * 16 + l16] = r;
        #pragma unroll
        for (int t = 0; t < 4; ++t)
            #pragma unroll
            for (int rr = 0; rr < 4; ++rr)
                Ob[(size_t)(q0w + i * 16 + q4 * 4 + rr) * DHEAD + t * 16 + l16] = o[i][t][rr];
    }
}

// ---------------------------------------------------------------------------
// Rec merge: attnb = bf16( (O0+O1) / (1e-12 + R0+R1) )
// ---------------------------------------------------------------------------
__launch_bounds__(256) __global__
void attn_merge_rec(const float* __restrict__ Opart, const float* __restrict__ Rpart,
                    unsigned short* __restrict__ attnb) {
    const size_t HALF_O = (size_t)BH * NQ * DHEAD;
    const size_t HALF_R = (size_t)BH * NQ;
    const int m = blockIdx.x * 32 + (threadIdx.x >> 3);
    const int d0 = (threadIdx.x & 7) * 8;
    const int bh = m >> 11, q = m & 2047;
    const int b = bh >> 3, h = bh & 7;
    const float* O0 = Opart + (size_t)m * DHEAD + d0;
    const float* O1 = O0 + HALF_O;
    float rs = 1.0f / (1e-12f + Rpart[m] + Rpart[HALF_R + m]);
    unsigned short* dst = attnb + ((size_t)b * NQ + q) * DMODEL + h * DHEAD + d0;
    #pragma unroll
    for (int e = 0; e < 8; ++e)
        dst[e] = f2b((O0[e] + O1[e]) * rs);
}

// ---------------------------------------------------------------------------
// Final: out[m][n] = Z[m][n] - sum_k attnb[m][k] * W01t[n][k]   (f32 out)
// ---------------------------------------------------------------------------
__launch_bounds__(256) __global__
void final_gemm(const unsigned short* __restrict__ A,
                const unsigned short* __restrict__ Bt,
                const float* __restrict__ Z, float* __restrict__ out) {
    const int K = DMODEL;
    const int tid = threadIdx.x;
    const int w = tid >> 6, lane = tid & 63;
    const int l16 = lane & 15, q4 = lane >> 4;
    const int mBase = blockIdx.x * 128 + w * 32;
    const int n0 = blockIdx.y * 64;

    const unsigned short* Arow0 = A + (size_t)(mBase + l16) * K;
    const unsigned short* Arow1 = Arow0 + (size_t)16 * K;
    const unsigned short* Brow0 = Bt + (size_t)(n0 + l16) * K;

    f32x4 zf = {0.f, 0.f, 0.f, 0.f};
    f32x4 acc[2][4];
    #pragma unroll
    for (int i = 0; i < 2; ++i)
        #pragma unroll
        for (int t = 0; t < 4; ++t) acc[i][t] = zf;

    #pragma unroll 2
    for (int k0 = 0; k0 < K; k0 += 32) {
        const int ko = k0 + q4 * 8;
        short8 a0 = *(const short8*)(Arow0 + ko);
        short8 a1 = *(const short8*)(Arow1 + ko);
        #pragma unroll
        for (int t = 0; t < 4; ++t) {
            short8 b = *(const short8*)(Brow0 + (size_t)t * 16 * K + ko);
            acc[0][t] = MFMA16(a0, b, acc[0][t]);
            acc[1][t] = MFMA16(a1, b, acc[1][t]);
        }
    }
    #pragma unroll
    for (int i = 0; i < 2; ++i)
        #pragma unroll
        for (int t = 0; t < 4; ++t)
            #pragma unroll
            for (int r = 0; r < 4; ++r) {
                const int m = mBase + i * 16 + q4 * 4 + r;
                const int n = n0 + t * 16 + l16;
                out[(size_t)m * DMODEL + n] = Z[(size_t)m * DMODEL + n] - acc[i][t][r];
            }
}

// ---------------------------------------------------------------------------
extern "C" void kernel_launch(void* const* d_in, const int* in_sizes, int n_in,
                              void* d_out, int out_size, void* d_ws, size_t ws_size,
                              hipStream_t stream) {
    const float* init_query = (const float*)d_in[0];
    const float* embedding  = (const float*)d_in[1];
    const float* Wq = (const float*)d_in[2];
    const float* Wk = (const float*)d_in[3];
    const float* Wv = (const float*)d_in[4];
    const float* W0 = (const float*)d_in[5];
    const float* b0 = (const float*)d_in[6];
    const float* W1 = (const float*)d_in[7];
    const float* b1 = (const float*)d_in[8];
    float* out = (float*)d_out;

    const size_t ACT = (size_t)BATCH * NQ * DMODEL;   // 4M elements
    const size_t WEL = (size_t)DMODEL * DMODEL;       // 256K elements

    unsigned short* Xq  = (unsigned short*)d_ws;
    unsigned short* Xe  = Xq + ACT;
    unsigned short* Wt  = Xe + ACT;                        // Wqt|Wkt|Wvt|W1t|W0b|W01t
    unsigned short* Qh  = Wt + 6 * WEL;
    unsigned short* Kh  = Qh + ACT;
    unsigned short* Vp  = Kh + ACT;                        // [bh][80][kc]
    float* colPart = (float*)(Vp + (size_t)BH * VROWS * NKEY);  // [2][bh][kc]
    float* colSrcp = colPart + 2 * (size_t)BH * NKEY;      // [bh][kc] (rec only)
    float* Z    = colSrcp + (size_t)BH * NKEY;             // [8192][512] f32
    float* bvec = Z + ACT;                                 // [512]
    float* Opart = bvec + DMODEL;                          // [2][bh][q][64] f32 (P path uses plane 0)
    float* Rpart = Opart + 2 * ACT;                        // [2][bh][q] f32
    unsigned short* PfTail = (unsigned short*)(Rpart + 2 * (size_t)BH * NQ);
    unsigned short* W01t = Wt + 5 * WEL;
    unsigned short* attnb = Xe;  // Xe dead after qkvz_gemm

    const size_t baseBytes = (size_t)((char*)PfTail - (char*)d_ws);
    const size_t pTot = (size_t)BH * NKEY * NQ * 2;   // 268.4 MB full-P bytes

    // pick kc-split factor S: P holds NKEY/S columns; smaller S = fewer groups
    int S = 0;
    unsigned short* Pf = nullptr;
    if (ws_size >= baseBytes + pTot / 2)       { S = 2;  Pf = PfTail; }
    else if (ws_size >= baseBytes + pTot / 4)  { S = 4;  Pf = PfTail; }
    else if (ws_size >= baseBytes + pTot / 8)  { S = 8;  Pf = PfTail; }
    else if (ws_size >= baseBytes + pTot / 16) { S = 16; Pf = PfTail; }
    else if (ws_size >= baseBytes)             { S = 16; Pf = Xq; }   // overlay (Xq+Xe dead)
    const int useP = (S != 0);

    dim3 blk(256);

    cast_x<<<dim3(ACT / 1024, 2), blk, 0, stream>>>(init_query, embedding, Xq, Xe);
    trans_w<<<dim3(16, 16, 5), blk, 0, stream>>>(Wq, Wk, Wv, W1, W0, Wt);
    bvec_kernel<<<dim3(8), blk, 0, stream>>>(b0, b1, W1, bvec);

    qkvz_gemm<<<dim3(64, 8, 5), blk, 0, stream>>>(Xq, Xe, Wt, Qh, Kh, Vp, Z, W01t, bvec, useP);

    if (useP) {
        const int C = 64 / S;  // 32-chunks per group
        for (int h = 0; h < S; ++h) {
            const int c0 = h * C;
            attn_pass1_p<<<dim3(C / 4, BH, 2), blk, 0, stream>>>(Qh, Kh, Pf, colPart, c0, C);
            vscale_merge<<<dim3(40 * C), blk, 0, stream>>>(colPart, Vp, c0, C);
            attn_pass2_p<<<dim3(16, BH), blk, 0, stream>>>(Pf, Vp, Opart, Rpart, c0, C, h > 0 ? 1 : 0);
        }
        attn_merge_p<<<dim3(BH * NQ / 32), blk, 0, stream>>>(Opart, Rpart, attnb);
    } else {
        attn_pass1_rec<<<dim3(16, BH, 2), blk, 0, stream>>>(Qh, Kh, colPart);
        col_merge<<<dim3(BH * NKEY / 1024), blk, 0, stream>>>(colPart, colSrcp);
        attn_pass2_rec<<<dim3(16, BH, 2), blk, 0, stream>>>(Qh, Kh, Vp, colSrcp, Opart, Rpart);
        attn_merge_rec<<<dim3(BH * NQ / 32), blk, 0, stream>>>(Opart, Rpart, attnb);
    }

    final_gemm<<<dim3(64, 8), blk, 0, stream>>>(attnb, W01t, Z, out);
}